// Round 8
// baseline (17061.617 us; speedup 1.0000x reference)
//
#include <hip/hip_runtime.h>

#define HIDDEN 512
#define TSEQ 512
#define NKEYS 128

typedef short short8_t __attribute__((ext_vector_type(8)));
typedef short short4_t __attribute__((ext_vector_type(4)));
typedef float f32x4 __attribute__((ext_vector_type(4)));

__device__ __forceinline__ ushort f2bf(float f) {
    union { float f; unsigned u; } v; v.f = f;
    unsigned r = (v.u + 0x7FFFu + ((v.u >> 16) & 1u)) >> 16;
    return (ushort)r;
}
__device__ __forceinline__ float sigm(float x) { return 1.0f / (1.0f + __expf(-x)); }
__device__ __forceinline__ float tanh_f(float x) { return 2.0f / (1.0f + __expf(-2.0f * x)) - 1.0f; }

__device__ __forceinline__ void async16(const void* g, void* l) {
    __builtin_amdgcn_global_load_lds((const __attribute__((address_space(1))) unsigned int*)g,
                                     (__attribute__((address_space(3))) unsigned int*)l, 16, 0, 0);
}

// Plain row-major bf16 cast of [W_ih | W_hh]: Wc[row*K + k].
__global__ void cast_w(const float* __restrict__ Wih, const float* __restrict__ Whh,
                       ushort* __restrict__ Wc, int KIN, int K) {
    long idx = (long)blockIdx.x * blockDim.x + threadIdx.x;
    if (idx >= (long)2048 * K) return;
    int row = (int)(idx / K), k = (int)(idx % K);
    float v = (k < KIN) ? Wih[(long)row * KIN + k] : Whh[(long)row * HIDDEN + (k - KIN)];
    Wc[idx] = f2bf(v);
}

__global__ void prep_bias(const float* __restrict__ a, const float* __restrict__ b,
                          const float* __restrict__ c, const float* __restrict__ d,
                          float* __restrict__ b0, float* __restrict__ b1) {
    int i = blockIdx.x * blockDim.x + threadIdx.x;
    if (i < 2048) { b0[i] = a[i] + b[i]; b1[i] = c[i] + d[i]; }
}

// Zero h0buf slot 0 (h(-1) for L0) and h1par parity 0 (h(-1) for L1).
__global__ void init_zeros(ushort* __restrict__ h0buf, ushort* __restrict__ h1par) {
    int idx = blockIdx.x * blockDim.x + threadIdx.x;   // 65536 threads, ushort4 each
    ushort4 z = {0, 0, 0, 0};
    if (idx < 32768) {
        int b = idx >> 7, off = (idx & 127) * 4;
        *(ushort4*)(h0buf + (size_t)b * 513 * 512 + off) = z;
    } else {
        int j = idx - 32768;
        *(ushort4*)(h1par + (size_t)j * 4) = z;
    }
}

// ---- named weight registers (SROA-proof) ----
#define AF_LIST_20(M) M(0)M(1)M(2)M(3)M(4)M(5)M(6)M(7)M(8)M(9)M(10)M(11)M(12)M(13)M(14)M(15)M(16)M(17)M(18)M(19)
#define AF_LIST_32(M) AF_LIST_20(M) M(20)M(21)M(22)M(23)M(24)M(25)M(26)M(27)M(28)M(29)M(30)M(31)

#define AF_DECL(i) short8_t af##i;
#define AF_LOAD(i) af##i = *(const short8_t*)(wsrc + (i) * 32);
#define AF_MFMA(i) { short8_t bf = *(const short8_t*)(bp + (i) * 64);                      \
    if ((i) & 1) acc1 = __builtin_amdgcn_mfma_f32_16x16x32_bf16(af##i, bf, acc1, 0, 0, 0); \
    else         acc0 = __builtin_amdgcn_mfma_f32_16x16x32_bf16(af##i, bf, acc0, 0, 0, 0); }

// Weight-stationary LSTM phase. Cooperative, grid=256 (1 block/CU), block=512.
// ANTI-SPILL (rounds 5-7 post-mortem): with small LDS, 4 blocks/CU fit, so the
// allocator targets 8 waves/EU (VGPR=64) and spills the loop-invariant weight
// regs to scratch; 4B-interleaved scratch reloads over-fetch 16x through L2
// (~19us/step, matches measured). Fix: (1) amdgpu_waves_per_eu(2,2) pins the
// occupancy target to 1 block/CU (VGPR budget 256); (2) LDS padded to 84KiB so
// >1 block/CU is physically impossible regardless of heuristics.
template <int MODE>
__global__ __attribute__((amdgpu_waves_per_eu(2, 2))) __launch_bounds__(512)
void lstm_phase(
    const float* __restrict__ x, const ushort* __restrict__ Wc,
    const float* __restrict__ biasc, ushort* __restrict__ h0buf,
    ushort* __restrict__ h1par, float* __restrict__ hlast,
    int* __restrict__ flags)
{
    constexpr int K  = MODE ? 1024 : 640;
    constexpr int RS = K + 8;                       // row stride (ushorts); +16B pad spreads banks
    constexpr int PAD_USHORT = (86016 - 16 * RS * 2) / 2;   // total LDS = 84 KiB -> 1 block/CU
    __shared__ __align__(16) ushort lds[16 * RS];
    __shared__ ushort lds_pad[PAD_USHORT];

    const int tid = threadIdx.x, bid = blockIdx.x;
    // keep lds_pad alive (runtime-unprovable branch; never taken)
    if ((size_t)flags == 1) ((volatile ushort*)lds_pad)[0] = (ushort)tid;

    const int tile = (bid & 7) * 2 + (bid >> 7);    // 16 blocks of a tile share an XCD (bid%8)
    const int g    = (bid >> 3) & 15;
    const int b0   = tile * 16;
    const int w = tid >> 6, lane = tid & 63, hi4 = lane >> 4, arow = lane & 15;
    const int Uw = g * 32 + w * 4;
    const int row_l = 512 * (arow & 3) + Uw + (arow >> 2);
    int* cnt = flags + (MODE ? 16 : 0) + tile;

    // ---- weights -> named VGPRs (once) ----
    AF_LIST_32(AF_DECL)
    {
        const ushort* wsrc = Wc + (size_t)row_l * K + hi4 * 8;
        if constexpr (MODE == 0) { AF_LIST_20(AF_LOAD) }
        else                     { AF_LIST_32(AF_LOAD) }
    }
    f32x4 bias4;
#pragma unroll
    for (int r = 0; r < 4; ++r) bias4[r] = biasc[512 * r + Uw + hi4];

    float c = 0.0f;
    const int r0 = w * 2, r1 = r0 + 1;              // LDS rows this wave stages
    char* const buf = (char*)lds;

#pragma unroll 1
    for (int t = 0; t < TSEQ; ++t) {
        // ---- S1: independent half (no flag needed) ----
        if (MODE == 0) {
            const int si = tid >> 5, sj = tid & 31;
            float4 v = *(const float4*)(x + (((size_t)(b0 + si)) * TSEQ + t) * NKEYS + sj * 4);
            short4_t s;
            s[0] = (short)f2bf(v.x); s[1] = (short)f2bf(v.y);
            s[2] = (short)f2bf(v.z); s[3] = (short)f2bf(v.w);
            *(short4_t*)(buf + si * (RS * 2) + sj * 8) = s;
        } else {
            async16(h0buf + ((size_t)(b0 + r0) * 513 + (t + 1)) * 512 + lane * 8, buf + r0 * (RS * 2));
            async16(h0buf + ((size_t)(b0 + r1) * 513 + (t + 1)) * 512 + lane * 8, buf + r1 * (RS * 2));
        }

        // ---- S2: wait for all 16 blocks' h(t-1) ----
        if (tid == 0) {
            while (__hip_atomic_load(cnt, __ATOMIC_ACQUIRE, __HIP_MEMORY_SCOPE_AGENT) < 16 * t)
                __builtin_amdgcn_s_sleep(1);
        }
        __syncthreads();   // B1

        // ---- S3: recurrent half ----
        if (MODE == 0) {
            async16(h0buf + ((size_t)(b0 + r0) * 513 + t) * 512 + lane * 8, buf + r0 * (RS * 2) + 256);
            async16(h0buf + ((size_t)(b0 + r1) * 513 + t) * 512 + lane * 8, buf + r1 * (RS * 2) + 256);
        } else {
            async16(h1par + ((size_t)(t & 1) * 256 + b0 + r0) * 512 + lane * 8, buf + r0 * (RS * 2) + 1024);
            async16(h1par + ((size_t)(t & 1) * 256 + b0 + r1) * 512 + lane * 8, buf + r1 * (RS * 2) + 1024);
        }
        asm volatile("s_waitcnt vmcnt(0)" ::: "memory");
        __syncthreads();   // B2: all 16 rows staged

        // ---- S5: MFMA sweep (weights from named VGPRs, B from LDS) ----
        f32x4 acc0 = bias4;
        f32x4 acc1 = {0.0f, 0.0f, 0.0f, 0.0f};
        const char* bp = buf + arow * (RS * 2) + hi4 * 16;
        if constexpr (MODE == 0) { AF_LIST_20(AF_MFMA) }
        else                     { AF_LIST_32(AF_MFMA) }
        f32x4 acc = acc0 + acc1;

        // ---- S6: elementwise (1 unit/lane) + publish h ----
        float ig = sigm(acc[0]), fg = sigm(acc[1]);
        float gg = tanh_f(acc[2]), og = sigm(acc[3]);
        c = fg * c + ig * gg;
        float h = og * tanh_f(c);
        int hv = f2bf(h);
        int v0 = __shfl(hv, arow, 64),      v1 = __shfl(hv, arow + 16, 64);
        int v2 = __shfl(hv, arow + 32, 64), v3 = __shfl(hv, arow + 48, 64);
        if (hi4 == 0) {
            ushort4 pk = { (ushort)v0, (ushort)v1, (ushort)v2, (ushort)v3 };
            if (MODE == 0)
                *(ushort4*)(h0buf + ((size_t)(b0 + arow) * 513 + (t + 1)) * 512 + Uw) = pk;
            else
                *(ushort4*)(h1par + ((size_t)((t + 1) & 1) * 256 + b0 + arow) * 512 + Uw) = pk;
        }
        if (MODE == 1 && t == TSEQ - 1)
            hlast[(size_t)(b0 + arow) * 512 + Uw + hi4] = h;

        asm volatile("s_waitcnt vmcnt(0)" ::: "memory");
        __syncthreads();   // B3: all waves' stores drained
        if (tid == 0)
            __hip_atomic_fetch_add(cnt, 1, __ATOMIC_RELEASE, __HIP_MEMORY_SCOPE_AGENT);
    }
}

__global__ void fc_kernel(const float* __restrict__ hlast, const float* __restrict__ Wfc,
                          const float* __restrict__ bfc, float* __restrict__ out) {
    __shared__ float hs[HIDDEN];
    const int b = blockIdx.x, n = threadIdx.x;   // 128 threads
    for (int k = n; k < HIDDEN; k += 128) hs[k] = hlast[b * HIDDEN + k];
    __syncthreads();
    const float* wr = Wfc + (long)n * HIDDEN;
    float acc = bfc[n];
#pragma unroll 8
    for (int k = 0; k < HIDDEN; ++k) acc += hs[k] * wr[k];
    out[b * 128 + n] = acc;
}

extern "C" void kernel_launch(void* const* d_in, const int* in_sizes, int n_in,
                              void* d_out, int out_size, void* d_ws, size_t ws_size,
                              hipStream_t stream) {
    const float* x    = (const float*)d_in[0];
    const float* Wih0 = (const float*)d_in[1];
    const float* Whh0 = (const float*)d_in[2];
    const float* bih0 = (const float*)d_in[3];
    const float* bhh0 = (const float*)d_in[4];
    const float* Wih1 = (const float*)d_in[5];
    const float* Whh1 = (const float*)d_in[6];
    const float* bih1 = (const float*)d_in[7];
    const float* bhh1 = (const float*)d_in[8];
    const float* Wfc  = (const float*)d_in[9];
    const float* bfc  = (const float*)d_in[10];

    char* ws = (char*)d_ws;
    size_t off = 0;
    auto alloc = [&](size_t bytes) {
        void* p = ws + off;
        off = (off + bytes + 255) & ~(size_t)255;
        return p;
    };
    ushort* Wc0   = (ushort*)alloc(2048UL * 640 * 2);         // 2.62 MB
    ushort* Wc1   = (ushort*)alloc(2048UL * 1024 * 2);        // 4.19 MB
    float*  bg0   = (float*)alloc(2048 * 4);
    float*  bg1   = (float*)alloc(2048 * 4);
    float*  hlast = (float*)alloc(256UL * 512 * 4);           // 0.52 MB
    ushort* h1par = (ushort*)alloc(2UL * 256 * 512 * 2);      // 0.52 MB
    int*    flags = (int*)alloc(256);
    ushort* h0buf = (ushort*)alloc(256UL * 513 * 512 * 2);    // 134.5 MB
    if (ws_size < off) return;

    hipMemsetAsync(flags, 0, 256, stream);
    init_zeros<<<256, 256, 0, stream>>>(h0buf, h1par);
    cast_w<<<(2048 * 640  + 255) / 256, 256, 0, stream>>>(Wih0, Whh0, Wc0, 128, 640);
    cast_w<<<(2048 * 1024 + 255) / 256, 256, 0, stream>>>(Wih1, Whh1, Wc1, 512, 1024);
    prep_bias<<<8, 256, 0, stream>>>(bih0, bhh0, bih1, bhh1, bg0, bg1);

    {
        void* args0[] = { (void*)&x, (void*)&Wc0, (void*)&bg0, (void*)&h0buf,
                          (void*)&h1par, (void*)&hlast, (void*)&flags };
        hipLaunchCooperativeKernel((const void*)lstm_phase<0>, dim3(256), dim3(512),
                                   args0, 0, stream);
    }
    {
        void* args1[] = { (void*)&x, (void*)&Wc1, (void*)&bg1, (void*)&h0buf,
                          (void*)&h1par, (void*)&hlast, (void*)&flags };
        hipLaunchCooperativeKernel((const void*)lstm_phase<1>, dim3(256), dim3(512),
                                   args1, 0, stream);
    }

    fc_kernel<<<256, 128, 0, stream>>>(hlast, Wfc, bfc, (float*)d_out);
}

// Round 9
// 8244.086 us; speedup vs baseline: 2.0696x; 2.0696x over previous
//
#include <hip/hip_runtime.h>

#define HIDDEN 512
#define TSEQ 512
#define NKEYS 128

typedef short short8_t __attribute__((ext_vector_type(8)));
typedef short short4_t __attribute__((ext_vector_type(4)));
typedef float f32x4 __attribute__((ext_vector_type(4)));

__device__ __forceinline__ ushort f2bf(float f) {
    union { float f; unsigned u; } v; v.f = f;
    unsigned r = (v.u + 0x7FFFu + ((v.u >> 16) & 1u)) >> 16;
    return (ushort)r;
}
__device__ __forceinline__ float sigm(float x) { return 1.0f / (1.0f + __expf(-x)); }
__device__ __forceinline__ float tanh_f(float x) { return 2.0f / (1.0f + __expf(-2.0f * x)) - 1.0f; }

__device__ __forceinline__ void async16(const void* g, void* l) {
    __builtin_amdgcn_global_load_lds((const __attribute__((address_space(1))) unsigned int*)g,
                                     (__attribute__((address_space(3))) unsigned int*)l, 16, 0, 0);
}

// Plain row-major bf16 cast of [W_ih | W_hh]: Wc[row*K + k].
__global__ void cast_w(const float* __restrict__ Wih, const float* __restrict__ Whh,
                       ushort* __restrict__ Wc, int KIN, int K) {
    long idx = (long)blockIdx.x * blockDim.x + threadIdx.x;
    if (idx >= (long)2048 * K) return;
    int row = (int)(idx / K), k = (int)(idx % K);
    float v = (k < KIN) ? Wih[(long)row * KIN + k] : Whh[(long)row * HIDDEN + (k - KIN)];
    Wc[idx] = f2bf(v);
}

__global__ void prep_bias(const float* __restrict__ a, const float* __restrict__ b,
                          const float* __restrict__ c, const float* __restrict__ d,
                          float* __restrict__ b0, float* __restrict__ b1) {
    int i = blockIdx.x * blockDim.x + threadIdx.x;
    if (i < 2048) { b0[i] = a[i] + b[i]; b1[i] = c[i] + d[i]; }
}

// Zero h0buf slot 0 (h(-1) for L0) and h1par parity 0 (h(-1) for L1).
__global__ void init_zeros(ushort* __restrict__ h0buf, ushort* __restrict__ h1par) {
    int idx = blockIdx.x * blockDim.x + threadIdx.x;   // 65536 threads, ushort4 each
    ushort4 z = {0, 0, 0, 0};
    if (idx < 32768) {
        int b = idx >> 7, off = (idx & 127) * 4;
        *(ushort4*)(h0buf + (size_t)b * 513 * 512 + off) = z;
    } else {
        int j = idx - 32768;
        *(ushort4*)(h1par + (size_t)j * 4) = z;
    }
}

// ---- named weight registers (SROA-proof) ----
#define AF_LIST_20(M) M(0)M(1)M(2)M(3)M(4)M(5)M(6)M(7)M(8)M(9)M(10)M(11)M(12)M(13)M(14)M(15)M(16)M(17)M(18)M(19)
#define AF_LIST_32(M) AF_LIST_20(M) M(20)M(21)M(22)M(23)M(24)M(25)M(26)M(27)M(28)M(29)M(30)M(31)

#define AF_DECL(i) short8_t af##i;
#define AF_LOAD(i) af##i = *(const short8_t*)(wsrc + (i) * 32);
#define AF_MFMA(i) { short8_t bf = *(const short8_t*)(bp + (i) * 64);                      \
    if ((i) & 1) acc1 = __builtin_amdgcn_mfma_f32_16x16x32_bf16(af##i, bf, acc1, 0, 0, 0); \
    else         acc0 = __builtin_amdgcn_mfma_f32_16x16x32_bf16(af##i, bf, acc0, 0, 0, 0); }

// Weight-stationary LSTM phase. Cooperative, grid=256 (1 block/CU), block=512.
// SYNC (round-8 post-mortem): r5-r8 all sat at ~19.5us/step with identical
// counters regardless of compute changes -> step time was dominated by 256
// blocks doing agent-scope fetch_add + acquire-polls on ONE 64-byte flag
// cacheline (serialized LLC RMWs ~= 13-38us/step). This round: one 128-B slot
// per (mode,tile,block); writers do a release STORE to their own slot (no RMW);
// waiters poll the tile's 16 slots in parallel (wave 0, lane&15) with
// __all(v >= t). Contention per line: 1 writer + same-XCD readers only.
template <int MODE>
__global__ __attribute__((amdgpu_waves_per_eu(2, 2))) __launch_bounds__(512)
void lstm_phase(
    const float* __restrict__ x, const ushort* __restrict__ Wc,
    const float* __restrict__ biasc, ushort* __restrict__ h0buf,
    ushort* __restrict__ h1par, float* __restrict__ hlast,
    int* __restrict__ flags)
{
    constexpr int K  = MODE ? 1024 : 640;
    constexpr int RS = K + 8;                       // row stride (ushorts); +16B pad spreads banks
    constexpr int PAD_USHORT = (86016 - 16 * RS * 2) / 2;   // total LDS = 84 KiB -> 1 block/CU
    __shared__ __align__(16) ushort lds[16 * RS];
    __shared__ ushort lds_pad[PAD_USHORT];

    const int tid = threadIdx.x, bid = blockIdx.x;
    // keep lds_pad alive (runtime-unprovable branch; never taken)
    if ((size_t)flags == 1) ((volatile ushort*)lds_pad)[0] = (ushort)tid;

    const int tile = (bid & 7) * 2 + (bid >> 7);    // 16 blocks of a tile share an XCD (bid%8)
    const int g    = (bid >> 3) & 15;
    const int b0   = tile * 16;
    const int w = tid >> 6, lane = tid & 63, hi4 = lane >> 4, arow = lane & 15;
    const int Uw = g * 32 + w * 4;
    const int row_l = 512 * (arow & 3) + Uw + (arow >> 2);
    // per-(mode,tile) slot array: 16 slots x 32 ints (128 B each)
    int* slots = flags + (MODE ? 8192 : 0) + tile * 512;

    // ---- weights -> named VGPRs (once) ----
    AF_LIST_32(AF_DECL)
    {
        const ushort* wsrc = Wc + (size_t)row_l * K + hi4 * 8;
        if constexpr (MODE == 0) { AF_LIST_20(AF_LOAD) }
        else                     { AF_LIST_32(AF_LOAD) }
    }
    f32x4 bias4;
#pragma unroll
    for (int r = 0; r < 4; ++r) bias4[r] = biasc[512 * r + Uw + hi4];

    float c = 0.0f;
    const int r0 = w * 2, r1 = r0 + 1;              // LDS rows this wave stages
    char* const buf = (char*)lds;
    const int* const pollp = slots + (lane & 15) * 32;

#pragma unroll 1
    for (int t = 0; t < TSEQ; ++t) {
        // ---- S1: independent half (no flag needed) ----
        if (MODE == 0) {
            const int si = tid >> 5, sj = tid & 31;
            float4 v = *(const float4*)(x + (((size_t)(b0 + si)) * TSEQ + t) * NKEYS + sj * 4);
            short4_t s;
            s[0] = (short)f2bf(v.x); s[1] = (short)f2bf(v.y);
            s[2] = (short)f2bf(v.z); s[3] = (short)f2bf(v.w);
            *(short4_t*)(buf + si * (RS * 2) + sj * 8) = s;
        } else {
            async16(h0buf + ((size_t)(b0 + r0) * 513 + (t + 1)) * 512 + lane * 8, buf + r0 * (RS * 2));
            async16(h0buf + ((size_t)(b0 + r1) * 513 + (t + 1)) * 512 + lane * 8, buf + r1 * (RS * 2));
        }

        // ---- S2: wait until all 16 blocks of this tile completed step t-1 ----
        if (w == 0) {
            while (true) {
                int v = __hip_atomic_load(pollp, __ATOMIC_ACQUIRE, __HIP_MEMORY_SCOPE_AGENT);
                if (__all(v >= t)) break;
                __builtin_amdgcn_s_sleep(2);
            }
        }
        __syncthreads();   // B1

        // ---- S3: recurrent half ----
        if (MODE == 0) {
            async16(h0buf + ((size_t)(b0 + r0) * 513 + t) * 512 + lane * 8, buf + r0 * (RS * 2) + 256);
            async16(h0buf + ((size_t)(b0 + r1) * 513 + t) * 512 + lane * 8, buf + r1 * (RS * 2) + 256);
        } else {
            async16(h1par + ((size_t)(t & 1) * 256 + b0 + r0) * 512 + lane * 8, buf + r0 * (RS * 2) + 1024);
            async16(h1par + ((size_t)(t & 1) * 256 + b0 + r1) * 512 + lane * 8, buf + r1 * (RS * 2) + 1024);
        }
        asm volatile("s_waitcnt vmcnt(0)" ::: "memory");
        __syncthreads();   // B2: all 16 rows staged

        // ---- S5: MFMA sweep (weights from named VGPRs, B from LDS) ----
        f32x4 acc0 = bias4;
        f32x4 acc1 = {0.0f, 0.0f, 0.0f, 0.0f};
        const char* bp = buf + arow * (RS * 2) + hi4 * 16;
        if constexpr (MODE == 0) { AF_LIST_20(AF_MFMA) }
        else                     { AF_LIST_32(AF_MFMA) }
        f32x4 acc = acc0 + acc1;

        // ---- S6: elementwise (1 unit/lane) + publish h ----
        float ig = sigm(acc[0]), fg = sigm(acc[1]);
        float gg = tanh_f(acc[2]), og = sigm(acc[3]);
        c = fg * c + ig * gg;
        float h = og * tanh_f(c);
        int hv = f2bf(h);
        int v0 = __shfl(hv, arow, 64),      v1 = __shfl(hv, arow + 16, 64);
        int v2 = __shfl(hv, arow + 32, 64), v3 = __shfl(hv, arow + 48, 64);
        if (hi4 == 0) {
            ushort4 pk = { (ushort)v0, (ushort)v1, (ushort)v2, (ushort)v3 };
            if (MODE == 0)
                *(ushort4*)(h0buf + ((size_t)(b0 + arow) * 513 + (t + 1)) * 512 + Uw) = pk;
            else
                *(ushort4*)(h1par + ((size_t)((t + 1) & 1) * 256 + b0 + arow) * 512 + Uw) = pk;
        }
        if (MODE == 1 && t == TSEQ - 1)
            hlast[(size_t)(b0 + arow) * 512 + Uw + hi4] = h;

        asm volatile("s_waitcnt vmcnt(0)" ::: "memory");
        __syncthreads();   // B3: all waves' stores drained
        if (tid == 0)
            __hip_atomic_store(slots + (g << 5), t + 1, __ATOMIC_RELEASE, __HIP_MEMORY_SCOPE_AGENT);
    }
}

__global__ void fc_kernel(const float* __restrict__ hlast, const float* __restrict__ Wfc,
                          const float* __restrict__ bfc, float* __restrict__ out) {
    __shared__ float hs[HIDDEN];
    const int b = blockIdx.x, n = threadIdx.x;   // 128 threads
    for (int k = n; k < HIDDEN; k += 128) hs[k] = hlast[b * HIDDEN + k];
    __syncthreads();
    const float* wr = Wfc + (long)n * HIDDEN;
    float acc = bfc[n];
#pragma unroll 8
    for (int k = 0; k < HIDDEN; ++k) acc += hs[k] * wr[k];
    out[b * 128 + n] = acc;
}

extern "C" void kernel_launch(void* const* d_in, const int* in_sizes, int n_in,
                              void* d_out, int out_size, void* d_ws, size_t ws_size,
                              hipStream_t stream) {
    const float* x    = (const float*)d_in[0];
    const float* Wih0 = (const float*)d_in[1];
    const float* Whh0 = (const float*)d_in[2];
    const float* bih0 = (const float*)d_in[3];
    const float* bhh0 = (const float*)d_in[4];
    const float* Wih1 = (const float*)d_in[5];
    const float* Whh1 = (const float*)d_in[6];
    const float* bih1 = (const float*)d_in[7];
    const float* bhh1 = (const float*)d_in[8];
    const float* Wfc  = (const float*)d_in[9];
    const float* bfc  = (const float*)d_in[10];

    char* ws = (char*)d_ws;
    size_t off = 0;
    auto alloc = [&](size_t bytes) {
        void* p = ws + off;
        off = (off + bytes + 255) & ~(size_t)255;
        return p;
    };
    ushort* Wc0   = (ushort*)alloc(2048UL * 640 * 2);         // 2.62 MB
    ushort* Wc1   = (ushort*)alloc(2048UL * 1024 * 2);        // 4.19 MB
    float*  bg0   = (float*)alloc(2048 * 4);
    float*  bg1   = (float*)alloc(2048 * 4);
    float*  hlast = (float*)alloc(256UL * 512 * 4);           // 0.52 MB
    ushort* h1par = (ushort*)alloc(2UL * 256 * 512 * 2);      // 0.52 MB
    int*    flags = (int*)alloc(65536);                       // 2x16x16 slots, 128B each
    ushort* h0buf = (ushort*)alloc(256UL * 513 * 512 * 2);    // 134.5 MB
    if (ws_size < off) return;

    hipMemsetAsync(flags, 0, 65536, stream);
    init_zeros<<<256, 256, 0, stream>>>(h0buf, h1par);
    cast_w<<<(2048 * 640  + 255) / 256, 256, 0, stream>>>(Wih0, Whh0, Wc0, 128, 640);
    cast_w<<<(2048 * 1024 + 255) / 256, 256, 0, stream>>>(Wih1, Whh1, Wc1, 512, 1024);
    prep_bias<<<8, 256, 0, stream>>>(bih0, bhh0, bih1, bhh1, bg0, bg1);

    {
        void* args0[] = { (void*)&x, (void*)&Wc0, (void*)&bg0, (void*)&h0buf,
                          (void*)&h1par, (void*)&hlast, (void*)&flags };
        hipLaunchCooperativeKernel((const void*)lstm_phase<0>, dim3(256), dim3(512),
                                   args0, 0, stream);
    }
    {
        void* args1[] = { (void*)&x, (void*)&Wc1, (void*)&bg1, (void*)&h0buf,
                          (void*)&h1par, (void*)&hlast, (void*)&flags };
        hipLaunchCooperativeKernel((const void*)lstm_phase<1>, dim3(256), dim3(512),
                                   args1, 0, stream);
    }

    fc_kernel<<<256, 128, 0, stream>>>(hlast, Wfc, bfc, (float*)d_out);
}

// Round 10
// 2819.267 us; speedup vs baseline: 6.0518x; 2.9242x over previous
//
#include <hip/hip_runtime.h>

#define HIDDEN 512
#define TSEQ 512
#define NKEYS 128

typedef short short8_t __attribute__((ext_vector_type(8)));
typedef short short4_t __attribute__((ext_vector_type(4)));
typedef float f32x4 __attribute__((ext_vector_type(4)));
typedef int i32x4 __attribute__((ext_vector_type(4)));

__device__ __forceinline__ ushort f2bf(float f) {
    union { float f; unsigned u; } v; v.f = f;
    unsigned r = (v.u + 0x7FFFu + ((v.u >> 16) & 1u)) >> 16;
    return (ushort)r;
}
__device__ __forceinline__ float sigm(float x) { return 1.0f / (1.0f + __expf(-x)); }
__device__ __forceinline__ float tanh_f(float x) { return 2.0f / (1.0f + __expf(-2.0f * x)) - 1.0f; }

__device__ __forceinline__ void async16(const void* g, void* l) {
    __builtin_amdgcn_global_load_lds((const __attribute__((address_space(1))) unsigned int*)g,
                                     (__attribute__((address_space(3))) unsigned int*)l, 16, 0, 0);
}

// Plain row-major bf16 cast of [W_ih | W_hh]: Wc[row*K + k].
__global__ void cast_w(const float* __restrict__ Wih, const float* __restrict__ Whh,
                       ushort* __restrict__ Wc, int KIN, int K) {
    long idx = (long)blockIdx.x * blockDim.x + threadIdx.x;
    if (idx >= (long)2048 * K) return;
    int row = (int)(idx / K), k = (int)(idx % K);
    float v = (k < KIN) ? Wih[(long)row * KIN + k] : Whh[(long)row * HIDDEN + (k - KIN)];
    Wc[idx] = f2bf(v);
}

__global__ void prep_bias(const float* __restrict__ a, const float* __restrict__ b,
                          const float* __restrict__ c, const float* __restrict__ d,
                          float* __restrict__ b0, float* __restrict__ b1) {
    int i = blockIdx.x * blockDim.x + threadIdx.x;
    if (i < 2048) { b0[i] = a[i] + b[i]; b1[i] = c[i] + d[i]; }
}

// Zero h0buf slot 0 (h(-1) for L0) and h1par parity 0 (h(-1) for L1).
__global__ void init_zeros(ushort* __restrict__ h0buf, ushort* __restrict__ h1par) {
    int idx = blockIdx.x * blockDim.x + threadIdx.x;   // 65536 threads, ushort4 each
    ushort4 z = {0, 0, 0, 0};
    if (idx < 32768) {
        int b = idx >> 7, off = (idx & 127) * 4;
        *(ushort4*)(h0buf + (size_t)b * 513 * 512 + off) = z;
    } else {
        int j = idx - 32768;
        *(ushort4*)(h1par + (size_t)j * 4) = z;
    }
}

// ---- named weight registers (SROA-proof) ----
#define AF_LIST_20(M) M(0)M(1)M(2)M(3)M(4)M(5)M(6)M(7)M(8)M(9)M(10)M(11)M(12)M(13)M(14)M(15)M(16)M(17)M(18)M(19)
#define AF_LIST_32(M) AF_LIST_20(M) M(20)M(21)M(22)M(23)M(24)M(25)M(26)M(27)M(28)M(29)M(30)M(31)

#define AF_DECL(i) short8_t af##i;
#define AF_LOAD(i) af##i = *(const short8_t*)(wsrc + (i) * 32);
#define AF_MFMA(i) { short8_t bf = *(const short8_t*)(bp + (i) * 64);                      \
    if ((i) & 1) acc1 = __builtin_amdgcn_mfma_f32_16x16x32_bf16(af##i, bf, acc1, 0, 0, 0); \
    else         acc0 = __builtin_amdgcn_mfma_f32_16x16x32_bf16(af##i, bf, acc0, 0, 0, 0); }

// Weight-stationary LSTM phase. Cooperative, grid=256 (1 block/CU), block=512.
// SYNC v3 (round-9 post-mortem): r9's residual 9us/step = coherence OPS, not
// contention: AGENT acquire emits an L2-invalidate per poll iteration and
// AGENT release an L2-writeback per step -> continuous XCD-L2 nuking explains
// flat FETCH=94MB and compute-insensitive step time. This round: NO atomics,
// NO fences. Flags and intra-kernel recurrent h move via explicit LLC-coherent
// plain ops (inline asm `sc0 sc1` loads/stores). Ordering: h stores -> vmcnt(0)
// -> barrier -> flag store (LLC is the single coherence point). Cross-kernel
// data (x, h0buf for MODE1-S1, hlast) keeps plain cached loads.
template <int MODE>
__global__ __attribute__((amdgpu_waves_per_eu(2, 2))) __launch_bounds__(512)
void lstm_phase(
    const float* __restrict__ x, const ushort* __restrict__ Wc,
    const float* __restrict__ biasc, ushort* __restrict__ h0buf,
    ushort* __restrict__ h1par, float* __restrict__ hlast,
    int* __restrict__ flags)
{
    constexpr int K   = MODE ? 1024 : 640;
    constexpr int KIN = MODE ? 512 : 128;
    constexpr int RS  = K + 8;                      // row stride (ushorts); +16B pad spreads banks
    constexpr int PAD_USHORT = (86016 - 16 * RS * 2) / 2;   // total LDS = 84 KiB -> 1 block/CU
    __shared__ __align__(16) ushort lds[16 * RS];
    __shared__ ushort lds_pad[PAD_USHORT];

    const int tid = threadIdx.x, bid = blockIdx.x;
    // keep lds_pad alive (runtime-unprovable branch; never taken)
    if ((size_t)flags == 1) ((volatile ushort*)lds_pad)[0] = (ushort)tid;

    const int tile = (bid & 7) * 2 + (bid >> 7);    // 16 blocks of a tile share an XCD (bid%8)
    const int g    = (bid >> 3) & 15;
    const int b0   = tile * 16;
    const int w = tid >> 6, lane = tid & 63, hi4 = lane >> 4, arow = lane & 15;
    const int Uw = g * 32 + w * 4;
    const int row_l = 512 * (arow & 3) + Uw + (arow >> 2);
    // per-(mode,tile) slot array: 16 slots x 32 ints (128 B each)
    int* slots = flags + (MODE ? 8192 : 0) + tile * 512;

    // ---- weights -> named VGPRs (once) ----
    AF_LIST_32(AF_DECL)
    {
        const ushort* wsrc = Wc + (size_t)row_l * K + hi4 * 8;
        if constexpr (MODE == 0) { AF_LIST_20(AF_LOAD) }
        else                     { AF_LIST_32(AF_LOAD) }
    }
    f32x4 bias4;
#pragma unroll
    for (int r = 0; r < 4; ++r) bias4[r] = biasc[512 * r + Uw + hi4];

    float c = 0.0f;
    const int r0 = w * 2, r1 = r0 + 1;              // LDS rows this wave stages
    char* const buf = (char*)lds;
    const unsigned long long pollA = (unsigned long long)(slots + (lane & 15) * 32);
    const unsigned long long flagA = (unsigned long long)(slots + (g << 5));

#pragma unroll 1
    for (int t = 0; t < TSEQ; ++t) {
        // ---- S1: independent half (no flag needed; cross-kernel data, cached) ----
        if (MODE == 0) {
            const int si = tid >> 5, sj = tid & 31;
            float4 v = *(const float4*)(x + (((size_t)(b0 + si)) * TSEQ + t) * NKEYS + sj * 4);
            short4_t s;
            s[0] = (short)f2bf(v.x); s[1] = (short)f2bf(v.y);
            s[2] = (short)f2bf(v.z); s[3] = (short)f2bf(v.w);
            *(short4_t*)(buf + si * (RS * 2) + sj * 8) = s;
        } else {
            async16(h0buf + ((size_t)(b0 + r0) * 513 + (t + 1)) * 512 + lane * 8, buf + r0 * (RS * 2));
            async16(h0buf + ((size_t)(b0 + r1) * 513 + (t + 1)) * 512 + lane * 8, buf + r1 * (RS * 2));
        }

        // ---- S2: wait until all 16 blocks of this tile completed step t-1 ----
        // Plain sc0sc1 dword load from LLC; no invalidates, no fences.
        if (w == 0) {
            while (true) {
                int v;
                asm volatile("global_load_dword %0, %1, off sc0 sc1\n\t"
                             "s_waitcnt vmcnt(0)"
                             : "=&v"(v) : "v"(pollA) : "memory");
                if (__all(v >= t)) break;
                __builtin_amdgcn_s_sleep(2);
            }
        }
        __syncthreads();   // B1

        // ---- S3: recurrent half via LLC-coherent loads -> LDS ----
        {
            const ushort* s0;
            const ushort* s1;
            if (MODE == 0) {
                s0 = h0buf + ((size_t)(b0 + r0) * 513 + t) * 512 + lane * 8;
                s1 = h0buf + ((size_t)(b0 + r1) * 513 + t) * 512 + lane * 8;
            } else {
                s0 = h1par + ((size_t)(t & 1) * 256 + b0 + r0) * 512 + lane * 8;
                s1 = h1par + ((size_t)(t & 1) * 256 + b0 + r1) * 512 + lane * 8;
            }
            i32x4 d0, d1;
            asm volatile("global_load_dwordx4 %0, %2, off sc0 sc1\n\t"
                         "global_load_dwordx4 %1, %3, off sc0 sc1\n\t"
                         "s_waitcnt vmcnt(0)"
                         : "=&v"(d0), "=&v"(d1)
                         : "v"((unsigned long long)s0), "v"((unsigned long long)s1)
                         : "memory");
            *(i32x4*)(buf + r0 * (RS * 2) + 2 * KIN + lane * 16) = d0;
            *(i32x4*)(buf + r1 * (RS * 2) + 2 * KIN + lane * 16) = d1;
        }
        __syncthreads();   // B2: all 16 rows staged (compiler adds lgkmcnt/vmcnt)

        // ---- S5: MFMA sweep (weights from named VGPRs, B from LDS) ----
        f32x4 acc0 = bias4;
        f32x4 acc1 = {0.0f, 0.0f, 0.0f, 0.0f};
        const char* bp = buf + arow * (RS * 2) + hi4 * 16;
        if constexpr (MODE == 0) { AF_LIST_20(AF_MFMA) }
        else                     { AF_LIST_32(AF_MFMA) }
        f32x4 acc = acc0 + acc1;

        // ---- S6: elementwise (1 unit/lane) + publish h to LLC ----
        float ig = sigm(acc[0]), fg = sigm(acc[1]);
        float gg = tanh_f(acc[2]), og = sigm(acc[3]);
        c = fg * c + ig * gg;
        float h = og * tanh_f(c);
        int hv = f2bf(h);
        int v0 = __shfl(hv, arow, 64),      v1 = __shfl(hv, arow + 16, 64);
        int v2 = __shfl(hv, arow + 32, 64), v3 = __shfl(hv, arow + 48, 64);
        if (hi4 == 0) {
            unsigned lo = (v0 & 0xFFFF) | (v1 << 16);
            unsigned hi = (v2 & 0xFFFF) | (v3 << 16);
            unsigned long long pk = (unsigned long long)lo | ((unsigned long long)hi << 32);
            const ushort* dst = (MODE == 0)
                ? h0buf + ((size_t)(b0 + arow) * 513 + (t + 1)) * 512 + Uw
                : h1par + ((size_t)((t + 1) & 1) * 256 + b0 + arow) * 512 + Uw;
            asm volatile("global_store_dwordx2 %0, %1, off sc0 sc1"
                         :: "v"((unsigned long long)dst), "v"(pk) : "memory");
        }
        if (MODE == 1 && t == TSEQ - 1)
            hlast[(size_t)(b0 + arow) * 512 + Uw + hi4] = h;

        asm volatile("s_waitcnt vmcnt(0)" ::: "memory");
        __syncthreads();   // B3: all waves' h stores completed at LLC
        if (tid == 0)
            asm volatile("global_store_dword %0, %1, off sc0 sc1"
                         :: "v"(flagA), "v"(t + 1) : "memory");
    }
}

__global__ void fc_kernel(const float* __restrict__ hlast, const float* __restrict__ Wfc,
                          const float* __restrict__ bfc, float* __restrict__ out) {
    __shared__ float hs[HIDDEN];
    const int b = blockIdx.x, n = threadIdx.x;   // 128 threads
    for (int k = n; k < HIDDEN; k += 128) hs[k] = hlast[b * HIDDEN + k];
    __syncthreads();
    const float* wr = Wfc + (long)n * HIDDEN;
    float acc = bfc[n];
#pragma unroll 8
    for (int k = 0; k < HIDDEN; ++k) acc += hs[k] * wr[k];
    out[b * 128 + n] = acc;
}

extern "C" void kernel_launch(void* const* d_in, const int* in_sizes, int n_in,
                              void* d_out, int out_size, void* d_ws, size_t ws_size,
                              hipStream_t stream) {
    const float* x    = (const float*)d_in[0];
    const float* Wih0 = (const float*)d_in[1];
    const float* Whh0 = (const float*)d_in[2];
    const float* bih0 = (const float*)d_in[3];
    const float* bhh0 = (const float*)d_in[4];
    const float* Wih1 = (const float*)d_in[5];
    const float* Whh1 = (const float*)d_in[6];
    const float* bih1 = (const float*)d_in[7];
    const float* bhh1 = (const float*)d_in[8];
    const float* Wfc  = (const float*)d_in[9];
    const float* bfc  = (const float*)d_in[10];

    char* ws = (char*)d_ws;
    size_t off = 0;
    auto alloc = [&](size_t bytes) {
        void* p = ws + off;
        off = (off + bytes + 255) & ~(size_t)255;
        return p;
    };
    ushort* Wc0   = (ushort*)alloc(2048UL * 640 * 2);         // 2.62 MB
    ushort* Wc1   = (ushort*)alloc(2048UL * 1024 * 2);        // 4.19 MB
    float*  bg0   = (float*)alloc(2048 * 4);
    float*  bg1   = (float*)alloc(2048 * 4);
    float*  hlast = (float*)alloc(256UL * 512 * 4);           // 0.52 MB
    ushort* h1par = (ushort*)alloc(2UL * 256 * 512 * 2);      // 0.52 MB
    int*    flags = (int*)alloc(65536);                       // 2x16x16 slots, 128B each
    ushort* h0buf = (ushort*)alloc(256UL * 513 * 512 * 2);    // 134.5 MB
    if (ws_size < off) return;

    hipMemsetAsync(flags, 0, 65536, stream);
    init_zeros<<<256, 256, 0, stream>>>(h0buf, h1par);
    cast_w<<<(2048 * 640  + 255) / 256, 256, 0, stream>>>(Wih0, Whh0, Wc0, 128, 640);
    cast_w<<<(2048 * 1024 + 255) / 256, 256, 0, stream>>>(Wih1, Whh1, Wc1, 512, 1024);
    prep_bias<<<8, 256, 0, stream>>>(bih0, bhh0, bih1, bhh1, bg0, bg1);

    {
        void* args0[] = { (void*)&x, (void*)&Wc0, (void*)&bg0, (void*)&h0buf,
                          (void*)&h1par, (void*)&hlast, (void*)&flags };
        hipLaunchCooperativeKernel((const void*)lstm_phase<0>, dim3(256), dim3(512),
                                   args0, 0, stream);
    }
    {
        void* args1[] = { (void*)&x, (void*)&Wc1, (void*)&bg1, (void*)&h0buf,
                          (void*)&h1par, (void*)&hlast, (void*)&flags };
        hipLaunchCooperativeKernel((const void*)lstm_phase<1>, dim3(256), dim3(512),
                                   args1, 0, stream);
    }

    fc_kernel<<<256, 128, 0, stream>>>(hlast, Wfc, bfc, (float*)d_out);
}

// Round 11
// 2598.743 us; speedup vs baseline: 6.5653x; 1.0849x over previous
//
#include <hip/hip_runtime.h>

#define HIDDEN 512
#define TSEQ 512
#define NKEYS 128

typedef short short8_t __attribute__((ext_vector_type(8)));
typedef short short4_t __attribute__((ext_vector_type(4)));
typedef float f32x4 __attribute__((ext_vector_type(4)));
typedef int i32x4 __attribute__((ext_vector_type(4)));

__device__ __forceinline__ ushort f2bf(float f) {
    union { float f; unsigned u; } v; v.f = f;
    unsigned r = (v.u + 0x7FFFu + ((v.u >> 16) & 1u)) >> 16;
    return (ushort)r;
}
__device__ __forceinline__ float sigm(float x) { return 1.0f / (1.0f + __expf(-x)); }
__device__ __forceinline__ float tanh_f(float x) { return 2.0f / (1.0f + __expf(-2.0f * x)) - 1.0f; }

// Plain row-major bf16 cast of [W_ih | W_hh]: Wc[row*K + k].
__global__ void cast_w(const float* __restrict__ Wih, const float* __restrict__ Whh,
                       ushort* __restrict__ Wc, int KIN, int K) {
    long idx = (long)blockIdx.x * blockDim.x + threadIdx.x;
    if (idx >= (long)2048 * K) return;
    int row = (int)(idx / K), k = (int)(idx % K);
    float v = (k < KIN) ? Wih[(long)row * KIN + k] : Whh[(long)row * HIDDEN + (k - KIN)];
    Wc[idx] = f2bf(v);
}

__global__ void prep_bias(const float* __restrict__ a, const float* __restrict__ b,
                          const float* __restrict__ c, const float* __restrict__ d,
                          float* __restrict__ b0, float* __restrict__ b1) {
    int i = blockIdx.x * blockDim.x + threadIdx.x;
    if (i < 2048) { b0[i] = a[i] + b[i]; b1[i] = c[i] + d[i]; }
}

// Zero h0buf slot 0 (h(-1) for L0) and h1par parity 0 (h(-1) for L1).
__global__ void init_zeros(ushort* __restrict__ h0buf, ushort* __restrict__ h1par) {
    int idx = blockIdx.x * blockDim.x + threadIdx.x;   // 65536 threads, ushort4 each
    ushort4 z = {0, 0, 0, 0};
    if (idx < 32768) {
        int b = idx >> 7, off = (idx & 127) * 4;
        *(ushort4*)(h0buf + (size_t)b * 513 * 512 + off) = z;
    } else {
        int j = idx - 32768;
        *(ushort4*)(h1par + (size_t)j * 4) = z;
    }
}

// ---- named weight registers, pinned into AGPRs (r5-r10: allocator remats the
// loads at ANY occupancy setting, VGPR_Count stuck at 64-88. The "+a" pin makes
// the def unrematerializable and homes it in the (otherwise idle) AGPR half of
// the unified file; inline-asm MFMA consumes A straight from AGPR). ----
#define AF_LIST_20(M) M(0)M(1)M(2)M(3)M(4)M(5)M(6)M(7)M(8)M(9)M(10)M(11)M(12)M(13)M(14)M(15)M(16)M(17)M(18)M(19)
#define AF_LIST_32(M) AF_LIST_20(M) M(20)M(21)M(22)M(23)M(24)M(25)M(26)M(27)M(28)M(29)M(30)M(31)

#define AF_DECL(i) short8_t af##i;
#define AF_LOAD(i) af##i = *(const short8_t*)(wsrc + (i) * 32); \
                   asm volatile("" : "+a"(af##i));

// Two M-subtiles (batch rows arow and 16+arow) share each weight fragment.
#define AF_MFMA(i) { \
    const char* _b  = ((i) < KSI) ? (bpi + (i) * 64) : (bpr + ((i) - KSI) * 64); \
    const int   _rs = ((i) < KSI) ? (RSI * 2) : (RSR * 2); \
    short8_t bf0 = *(const short8_t*)_b; \
    short8_t bf1 = *(const short8_t*)(_b + 16 * _rs); \
    if ((i) & 1) { \
        asm("v_mfma_f32_16x16x32_bf16 %0, %1, %2, %0" : "+v"(accA1) : "a"(af##i), "v"(bf0)); \
        asm("v_mfma_f32_16x16x32_bf16 %0, %1, %2, %0" : "+v"(accB1) : "a"(af##i), "v"(bf1)); \
    } else { \
        asm("v_mfma_f32_16x16x32_bf16 %0, %1, %2, %0" : "+v"(accA0) : "a"(af##i), "v"(bf0)); \
        asm("v_mfma_f32_16x16x32_bf16 %0, %1, %2, %0" : "+v"(accB0) : "a"(af##i), "v"(bf1)); \
    } }

// Fused 2-layer LSTM, layer-pipelined. Cooperative grid=256 (1 block/CU).
// bid<128: layer0 (8 tiles x 16 g-blocks, 32 batch rows/tile); bid>=128: layer1.
// L1 step t consumes h0(t) (h0buf slot t+1, polled via L0 flags >= t+1) and its
// own h1(t-1); runs ~1 step behind L0 on disjoint CUs -> wall ~= 513 steps.
// All cross-block data/flags via LLC-coherent sc0sc1 ops (r10-validated).
template <int L>
__device__ __forceinline__ void lstm_body(
    char* smem, int bid,
    const float* __restrict__ x, const ushort* __restrict__ Wc,
    const float* __restrict__ biasc, ushort* __restrict__ h0buf,
    ushort* __restrict__ h1par, float* __restrict__ hlast, int* flags)
{
    constexpr int KIN = L ? 512 : 128;
    constexpr int K   = KIN + 512;
    constexpr int KSI = KIN / 32;       // input-half k-steps (4 / 16)
    constexpr int RSI = KIN + 8;        // inbuf row stride (ushorts)
    constexpr int RSR = 520;            // recbuf row stride (ushorts)
    constexpr size_t RST0 = 513 * 512;  // h0buf batch-row stride (ushorts)

    char* const recb  = smem;           // 32 x RSR x 2 = 33280 B
    char* const inb   = smem + 33280;   // 32 x RSI x 2
    char* const stage = smem + 66560;   // 32 rows x 64 B

    const int tid = threadIdx.x;
    const int lb = bid & 127, tile = lb >> 4, g = lb & 15, b0 = tile * 32;
    const int w = tid >> 6, lane = tid & 63, hi4 = lane >> 4, arow = lane & 15;
    const int Uw = g * 32 + w * 4;
    const int row_l = 512 * (arow & 3) + Uw + (arow >> 2);

    int* const ownbase  = flags + (L ? 4096 : 0) + tile * 512;  // 16 slots x 128 B
    int* const prodbase = flags + tile * 512;                   // L0 slots (for L1)
    int* const myflag   = ownbase + g * 32;

    // ---- weights -> AGPRs (once) ----
    AF_LIST_32(AF_DECL)
    {
        const ushort* wsrc = Wc + (size_t)row_l * K + hi4 * 8;
        if constexpr (L == 0) { AF_LIST_20(AF_LOAD) }
        else                  { AF_LIST_32(AF_LOAD) }
    }
    f32x4 bias4;
#pragma unroll
    for (int r = 0; r < 4; ++r) bias4[r] = biasc[512 * r + Uw + hi4];

    float c0 = 0.0f, c1 = 0.0f;

    // x prefetch registers (L0): row si, 8 floats at sj*8
    const int si = tid >> 4, sj = tid & 15;
    float4 xa, xb;
    if constexpr (L == 0) {
        const float* xp = x + ((size_t)(b0 + si) * TSEQ + 0) * NKEYS + sj * 8;
        xa = *(const float4*)xp; xb = *(const float4*)(xp + 4);
    }

    // poll setup: L0: 16 own slots >= t; L1: 16 own >= t and 16 producer >= t+1
    const int* pollp; int thrAdd;
    if constexpr (L == 0) {
        pollp = ownbase + (lane & 15) * 32; thrAdd = 0;
    } else {
        const int prod = (lane >> 4) & 1;
        pollp = (prod ? prodbase : ownbase) + (lane & 15) * 32;
        thrAdd = prod;
    }

#pragma unroll 1
    for (int t = 0; t < TSEQ; ++t) {
        // ---- S1 (L0): cvt prefetched x -> inbuf ----
        if constexpr (L == 0) {
            short8_t s;
            s[0] = (short)f2bf(xa.x); s[1] = (short)f2bf(xa.y);
            s[2] = (short)f2bf(xa.z); s[3] = (short)f2bf(xa.w);
            s[4] = (short)f2bf(xb.x); s[5] = (short)f2bf(xb.y);
            s[6] = (short)f2bf(xb.z); s[7] = (short)f2bf(xb.w);
            *(short8_t*)(inb + si * (RSI * 2) + sj * 16) = s;
        }

        // ---- S2: wave 1 polls (wave 0 may still be publishing prev step) ----
        if (w == 1) {
            const int thr = t + thrAdd;
            while (true) {
                int v;
                asm volatile("global_load_dword %0, %1, off sc0 sc1\n\t"
                             "s_waitcnt vmcnt(0)"
                             : "=&v"(v) : "v"((unsigned long long)pollp) : "memory");
                if (__all(v >= thr)) break;
                __builtin_amdgcn_s_sleep(1);
            }
        }
        __syncthreads();   // B1

        // ---- S3: LLC-coherent loads -> LDS (wave w stages rows 4w..4w+3) ----
        {
            i32x4 r0, r1, r2, r3;
            if constexpr (L == 0) {
                const ushort* rb = h0buf + ((size_t)(b0 + w * 4) * 513 + t) * 512 + lane * 8;
                asm volatile("global_load_dwordx4 %0, %4, off sc0 sc1\n\t"
                             "global_load_dwordx4 %1, %5, off sc0 sc1\n\t"
                             "global_load_dwordx4 %2, %6, off sc0 sc1\n\t"
                             "global_load_dwordx4 %3, %7, off sc0 sc1\n\t"
                             "s_waitcnt vmcnt(0)"
                             : "=&v"(r0), "=&v"(r1), "=&v"(r2), "=&v"(r3)
                             : "v"((unsigned long long)rb),
                               "v"((unsigned long long)(rb + RST0)),
                               "v"((unsigned long long)(rb + 2 * RST0)),
                               "v"((unsigned long long)(rb + 3 * RST0))
                             : "memory");
            } else {
                const ushort* ib = h0buf + ((size_t)(b0 + w * 4) * 513 + (t + 1)) * 512 + lane * 8;
                const ushort* rb = h1par + ((size_t)((t & 1) * 256 + b0 + w * 4)) * 512 + lane * 8;
                i32x4 i0, i1, i2, i3;
                asm volatile("global_load_dwordx4 %0, %4, off sc0 sc1\n\t"
                             "global_load_dwordx4 %1, %5, off sc0 sc1\n\t"
                             "global_load_dwordx4 %2, %6, off sc0 sc1\n\t"
                             "global_load_dwordx4 %3, %7, off sc0 sc1"
                             : "=&v"(i0), "=&v"(i1), "=&v"(i2), "=&v"(i3)
                             : "v"((unsigned long long)ib),
                               "v"((unsigned long long)(ib + RST0)),
                               "v"((unsigned long long)(ib + 2 * RST0)),
                               "v"((unsigned long long)(ib + 3 * RST0))
                             : "memory");
                asm volatile("global_load_dwordx4 %0, %4, off sc0 sc1\n\t"
                             "global_load_dwordx4 %1, %5, off sc0 sc1\n\t"
                             "global_load_dwordx4 %2, %6, off sc0 sc1\n\t"
                             "global_load_dwordx4 %3, %7, off sc0 sc1\n\t"
                             "s_waitcnt vmcnt(0)"
                             : "=&v"(r0), "=&v"(r1), "=&v"(r2), "=&v"(r3)
                             : "v"((unsigned long long)rb),
                               "v"((unsigned long long)(rb + 512)),
                               "v"((unsigned long long)(rb + 2 * 512)),
                               "v"((unsigned long long)(rb + 3 * 512))
                             : "memory");
                *(i32x4*)(inb + (w * 4 + 0) * (RSI * 2) + lane * 16) = i0;
                *(i32x4*)(inb + (w * 4 + 1) * (RSI * 2) + lane * 16) = i1;
                *(i32x4*)(inb + (w * 4 + 2) * (RSI * 2) + lane * 16) = i2;
                *(i32x4*)(inb + (w * 4 + 3) * (RSI * 2) + lane * 16) = i3;
            }
            *(i32x4*)(recb + (w * 4 + 0) * (RSR * 2) + lane * 16) = r0;
            *(i32x4*)(recb + (w * 4 + 1) * (RSR * 2) + lane * 16) = r1;
            *(i32x4*)(recb + (w * 4 + 2) * (RSR * 2) + lane * 16) = r2;
            *(i32x4*)(recb + (w * 4 + 3) * (RSR * 2) + lane * 16) = r3;
        }
        // x prefetch for t+1 (issued after the vmcnt so it isn't waited here)
        if constexpr (L == 0) {
            const int tt = (t + 1) & 511;
            const float* xp = x + ((size_t)(b0 + si) * TSEQ + tt) * NKEYS + sj * 8;
            xa = *(const float4*)xp; xb = *(const float4*)(xp + 4);
        }
        __syncthreads();   // B2: all 32 rows staged

        // ---- S5: MFMA sweep (A from AGPR, B from LDS; 2 subtiles x 2 chains) ----
        f32x4 accA0 = bias4, accB0 = bias4;
        f32x4 accA1 = {0.f, 0.f, 0.f, 0.f}, accB1 = {0.f, 0.f, 0.f, 0.f};
        const char* bpi = inb  + arow * (RSI * 2) + hi4 * 16;
        const char* bpr = recb + arow * (RSR * 2) + hi4 * 16;
        if constexpr (L == 0) { AF_LIST_20(AF_MFMA) }
        else                  { AF_LIST_32(AF_MFMA) }
        asm volatile("s_nop 7\n\ts_nop 7"
                     : "+v"(accA0), "+v"(accA1), "+v"(accB0), "+v"(accB1));
        f32x4 am0 = accA0 + accA1, am1 = accB0 + accB1;

        // ---- S6: elementwise (2 units/lane: batch rows arow and 16+arow) ----
        float ig0 = sigm(am0[0]), fg0 = sigm(am0[1]);
        float gg0 = tanh_f(am0[2]), og0 = sigm(am0[3]);
        c0 = fg0 * c0 + ig0 * gg0;
        float h0f = og0 * tanh_f(c0);
        float ig1 = sigm(am1[0]), fg1 = sigm(am1[1]);
        float gg1 = tanh_f(am1[2]), og1 = sigm(am1[3]);
        c1 = fg1 * c1 + ig1 * gg1;
        float h1f = og1 * tanh_f(c1);
        *(ushort*)(stage + arow * 64 + w * 8 + hi4 * 2)        = f2bf(h0f);
        *(ushort*)(stage + (16 + arow) * 64 + w * 8 + hi4 * 2) = f2bf(h1f);
        if (L == 1 && t == TSEQ - 1) {
            hlast[(size_t)(b0 + arow) * 512 + Uw + hi4]      = h0f;
            hlast[(size_t)(b0 + 16 + arow) * 512 + Uw + hi4] = h1f;
        }
        __syncthreads();   // B3: stage visible

        // ---- S7 (wave 0): coalesced 64-B line publish + flag ----
        if (w == 0) {
            const int row = lane >> 2, q = lane & 3;
            i32x4 s0 = *(const i32x4*)(stage + row * 64 + q * 16);
            i32x4 s1 = *(const i32x4*)(stage + (row + 16) * 64 + q * 16);
            const ushort* d0;
            const ushort* d1;
            if constexpr (L == 0) {
                d0 = h0buf + ((size_t)(b0 + row) * 513 + (t + 1)) * 512 + g * 32 + q * 8;
                d1 = h0buf + ((size_t)(b0 + 16 + row) * 513 + (t + 1)) * 512 + g * 32 + q * 8;
            } else {
                const size_t par = (size_t)((t + 1) & 1) * 256;
                d0 = h1par + (par + b0 + row) * 512 + g * 32 + q * 8;
                d1 = h1par + (par + b0 + 16 + row) * 512 + g * 32 + q * 8;
            }
            asm volatile("global_store_dwordx4 %0, %2, off sc0 sc1\n\t"
                         "global_store_dwordx4 %1, %3, off sc0 sc1\n\t"
                         "s_waitcnt vmcnt(0)"
                         :: "v"((unsigned long long)d0), "v"((unsigned long long)d1),
                            "v"(s0), "v"(s1) : "memory");
            if (tid == 0)
                asm volatile("global_store_dword %0, %1, off sc0 sc1"
                             :: "v"((unsigned long long)myflag), "v"(t + 1) : "memory");
        }
    }
}

__global__ __attribute__((amdgpu_waves_per_eu(2, 2))) __launch_bounds__(512)
void lstm_fused(const float* __restrict__ x,
                const ushort* __restrict__ Wc0, const ushort* __restrict__ Wc1,
                const float* __restrict__ bg0, const float* __restrict__ bg1,
                ushort* __restrict__ h0buf, ushort* __restrict__ h1par,
                float* __restrict__ hlast, int* flags)
{
    __shared__ __align__(16) char smem[86016];   // > 80 KiB: physically 1 block/CU
    const int bid = blockIdx.x;
    if (bid < 128) lstm_body<0>(smem, bid, x, Wc0, bg0, h0buf, h1par, hlast, flags);
    else           lstm_body<1>(smem, bid, x, Wc1, bg1, h0buf, h1par, hlast, flags);
}

__global__ void fc_kernel(const float* __restrict__ hlast, const float* __restrict__ Wfc,
                          const float* __restrict__ bfc, float* __restrict__ out) {
    __shared__ float hs[HIDDEN];
    const int b = blockIdx.x, n = threadIdx.x;   // 128 threads
    for (int k = n; k < HIDDEN; k += 128) hs[k] = hlast[b * HIDDEN + k];
    __syncthreads();
    const float* wr = Wfc + (long)n * HIDDEN;
    float acc = bfc[n];
#pragma unroll 8
    for (int k = 0; k < HIDDEN; ++k) acc += hs[k] * wr[k];
    out[b * 128 + n] = acc;
}

extern "C" void kernel_launch(void* const* d_in, const int* in_sizes, int n_in,
                              void* d_out, int out_size, void* d_ws, size_t ws_size,
                              hipStream_t stream) {
    const float* x    = (const float*)d_in[0];
    const float* Wih0 = (const float*)d_in[1];
    const float* Whh0 = (const float*)d_in[2];
    const float* bih0 = (const float*)d_in[3];
    const float* bhh0 = (const float*)d_in[4];
    const float* Wih1 = (const float*)d_in[5];
    const float* Whh1 = (const float*)d_in[6];
    const float* bih1 = (const float*)d_in[7];
    const float* bhh1 = (const float*)d_in[8];
    const float* Wfc  = (const float*)d_in[9];
    const float* bfc  = (const float*)d_in[10];

    char* ws = (char*)d_ws;
    size_t off = 0;
    auto alloc = [&](size_t bytes) {
        void* p = ws + off;
        off = (off + bytes + 255) & ~(size_t)255;
        return p;
    };
    ushort* Wc0   = (ushort*)alloc(2048UL * 640 * 2);         // 2.62 MB
    ushort* Wc1   = (ushort*)alloc(2048UL * 1024 * 2);        // 4.19 MB
    float*  bg0   = (float*)alloc(2048 * 4);
    float*  bg1   = (float*)alloc(2048 * 4);
    float*  hlast = (float*)alloc(256UL * 512 * 4);           // 0.52 MB
    ushort* h1par = (ushort*)alloc(2UL * 256 * 512 * 2);      // 0.52 MB
    int*    flags = (int*)alloc(65536);                       // 2 layers x 8 tiles x 16 slots x 128 B
    ushort* h0buf = (ushort*)alloc(256UL * 513 * 512 * 2);    // 134.5 MB
    if (ws_size < off) return;

    hipMemsetAsync(flags, 0, 65536, stream);
    init_zeros<<<256, 256, 0, stream>>>(h0buf, h1par);
    cast_w<<<(2048 * 640  + 255) / 256, 256, 0, stream>>>(Wih0, Whh0, Wc0, 128, 640);
    cast_w<<<(2048 * 1024 + 255) / 256, 256, 0, stream>>>(Wih1, Whh1, Wc1, 512, 1024);
    prep_bias<<<8, 256, 0, stream>>>(bih0, bhh0, bih1, bhh1, bg0, bg1);

    {
        void* args[] = { (void*)&x, (void*)&Wc0, (void*)&Wc1, (void*)&bg0, (void*)&bg1,
                         (void*)&h0buf, (void*)&h1par, (void*)&hlast, (void*)&flags };
        hipLaunchCooperativeKernel((const void*)lstm_fused, dim3(256), dim3(512),
                                   args, 0, stream);
    }

    fc_kernel<<<256, 128, 0, stream>>>(hlast, Wfc, bfc, (float*)d_out);
}

// Round 12
// 2368.932 us; speedup vs baseline: 7.2022x; 1.0970x over previous
//
#include <hip/hip_runtime.h>

#define HIDDEN 512
#define TSEQ 512
#define NKEYS 128

typedef short short8_t __attribute__((ext_vector_type(8)));
typedef short short4_t __attribute__((ext_vector_type(4)));
typedef float f32x4 __attribute__((ext_vector_type(4)));
typedef int i32x4 __attribute__((ext_vector_type(4)));

__device__ __forceinline__ ushort f2bf(float f) {
    union { float f; unsigned u; } v; v.f = f;
    unsigned r = (v.u + 0x7FFFu + ((v.u >> 16) & 1u)) >> 16;
    return (ushort)r;
}
__device__ __forceinline__ float sigm(float x) { return 1.0f / (1.0f + __expf(-x)); }
__device__ __forceinline__ float tanh_f(float x) { return 2.0f / (1.0f + __expf(-2.0f * x)) - 1.0f; }

// Plain row-major bf16 cast of [W_ih | W_hh]: Wc[row*K + k].
__global__ void cast_w(const float* __restrict__ Wih, const float* __restrict__ Whh,
                       ushort* __restrict__ Wc, int KIN, int K) {
    long idx = (long)blockIdx.x * blockDim.x + threadIdx.x;
    if (idx >= (long)2048 * K) return;
    int row = (int)(idx / K), k = (int)(idx % K);
    float v = (k < KIN) ? Wih[(long)row * KIN + k] : Whh[(long)row * HIDDEN + (k - KIN)];
    Wc[idx] = f2bf(v);
}

__global__ void prep_bias(const float* __restrict__ a, const float* __restrict__ b,
                          const float* __restrict__ c, const float* __restrict__ d,
                          float* __restrict__ b0, float* __restrict__ b1) {
    int i = blockIdx.x * blockDim.x + threadIdx.x;
    if (i < 2048) { b0[i] = a[i] + b[i]; b1[i] = c[i] + d[i]; }
}

// Zero h0buf slot 0 (h(-1) for L0) and h1par parity 0 (h(-1) for L1).
__global__ void init_zeros(ushort* __restrict__ h0buf, ushort* __restrict__ h1par) {
    int idx = blockIdx.x * blockDim.x + threadIdx.x;   // 65536 threads, ushort4 each
    ushort4 z = {0, 0, 0, 0};
    if (idx < 32768) {
        int b = idx >> 7, off = (idx & 127) * 4;
        *(ushort4*)(h0buf + (size_t)b * 513 * 512 + off) = z;
    } else {
        int j = idx - 32768;
        *(ushort4*)(h1par + (size_t)j * 4) = z;
    }
}

// ---- named weight registers, pinned into AGPRs (r5-r10: allocator remats the
// loads at ANY occupancy setting. "+a" pin homes them in the AGPR half of the
// unified file; inline-asm MFMA consumes A straight from AGPR). ----
#define AF_LIST_20(M) M(0)M(1)M(2)M(3)M(4)M(5)M(6)M(7)M(8)M(9)M(10)M(11)M(12)M(13)M(14)M(15)M(16)M(17)M(18)M(19)
#define AF_LIST_32(M) AF_LIST_20(M) M(20)M(21)M(22)M(23)M(24)M(25)M(26)M(27)M(28)M(29)M(30)M(31)

#define AF_DECL(i) short8_t af##i;
#define AF_LOAD(i) af##i = *(const short8_t*)(wsrc + (i) * 32); \
                   asm volatile("" : "+a"(af##i));

// Two M-subtiles (batch rows arow and 16+arow) share each weight fragment.
#define AF_MFMA(i) { \
    const char* _b  = ((i) < KSI) ? (bpi + (i) * 64) : (bpr + ((i) - KSI) * 64); \
    const int   _rs = ((i) < KSI) ? (RSI * 2) : (RSR * 2); \
    short8_t bf0 = *(const short8_t*)_b; \
    short8_t bf1 = *(const short8_t*)(_b + 16 * _rs); \
    if ((i) & 1) { \
        asm("v_mfma_f32_16x16x32_bf16 %0, %1, %2, %0" : "+v"(accA1) : "a"(af##i), "v"(bf0)); \
        asm("v_mfma_f32_16x16x32_bf16 %0, %1, %2, %0" : "+v"(accB1) : "a"(af##i), "v"(bf1)); \
    } else { \
        asm("v_mfma_f32_16x16x32_bf16 %0, %1, %2, %0" : "+v"(accA0) : "a"(af##i), "v"(bf0)); \
        asm("v_mfma_f32_16x16x32_bf16 %0, %1, %2, %0" : "+v"(accB0) : "a"(af##i), "v"(bf1)); \
    } }

// Fused 2-layer LSTM, layer-pipelined, XCD-LOCAL (r11 post-mortem: spreading a
// tile's blocks across XCDs turned every h0 hand-off into an LLC/HBM round
// trip: FETCH 116MB -> 1.9GB, step 3.0 -> 5.2us. This mapping puts a tile's
// 16 L0 producers AND 16 L1 consumers on ONE XCD (32 blocks = 32 CUs): all
// h0/h1/flag traffic is XCD-local and the 16x consumer h0 fan-in hits L2.
// Correctness never depends on the mapping — sc0sc1 is LLC-coherent anywhere;
// placement only affects speed (Guideline 16).)
//   xcd/tile = bid & 7, j = bid >> 3 (0..31), L = j >> 4, g = j & 15.
template <int L>
__device__ __forceinline__ void lstm_body(
    char* smem, int bid,
    const float* __restrict__ x, const ushort* __restrict__ Wc,
    const float* __restrict__ biasc, ushort* __restrict__ h0buf,
    ushort* __restrict__ h1par, float* __restrict__ hlast, int* flags)
{
    constexpr int KIN = L ? 512 : 128;
    constexpr int K   = KIN + 512;
    constexpr int KSI = KIN / 32;       // input-half k-steps (4 / 16)
    constexpr int RSI = KIN + 8;        // inbuf row stride (ushorts)
    constexpr int RSR = 520;            // recbuf row stride (ushorts)
    constexpr size_t RST0 = 513 * 512;  // h0buf batch-row stride (ushorts)

    char* const recb  = smem;           // 32 x RSR x 2 = 33280 B
    char* const inb   = smem + 33280;   // 32 x RSI x 2
    char* const stage = smem + 66560;   // 32 rows x 64 B

    const int tid = threadIdx.x;
    const int tile = bid & 7;                 // tile == XCD (standard bid%8 mapping)
    const int g    = (bid >> 3) & 15;
    const int b0   = tile * 32;
    const int w = tid >> 6, lane = tid & 63, hi4 = lane >> 4, arow = lane & 15;
    const int Uw = g * 32 + w * 4;
    const int row_l = 512 * (arow & 3) + Uw + (arow >> 2);

    int* const ownbase  = flags + (L ? 4096 : 0) + tile * 512;  // 16 slots x 128 B
    int* const prodbase = flags + tile * 512;                   // L0 slots (for L1)
    int* const myflag   = ownbase + g * 32;

    // ---- weights -> AGPRs (once) ----
    AF_LIST_32(AF_DECL)
    {
        const ushort* wsrc = Wc + (size_t)row_l * K + hi4 * 8;
        if constexpr (L == 0) { AF_LIST_20(AF_LOAD) }
        else                  { AF_LIST_32(AF_LOAD) }
    }
    f32x4 bias4;
#pragma unroll
    for (int r = 0; r < 4; ++r) bias4[r] = biasc[512 * r + Uw + hi4];

    float c0 = 0.0f, c1 = 0.0f;

    // x prefetch registers (L0): row si, 8 floats at sj*8
    const int si = tid >> 4, sj = tid & 15;
    float4 xa, xb;
    if constexpr (L == 0) {
        const float* xp = x + ((size_t)(b0 + si) * TSEQ + 0) * NKEYS + sj * 8;
        xa = *(const float4*)xp; xb = *(const float4*)(xp + 4);
    }

    // poll setup: L0: 16 own slots >= t; L1: 16 own >= t and 16 producer >= t+1
    const int* pollp; int thrAdd;
    if constexpr (L == 0) {
        pollp = ownbase + (lane & 15) * 32; thrAdd = 0;
    } else {
        const int prod = (lane >> 4) & 1;
        pollp = (prod ? prodbase : ownbase) + (lane & 15) * 32;
        thrAdd = prod;
    }

#pragma unroll 1
    for (int t = 0; t < TSEQ; ++t) {
        // ---- S1 (L0): cvt prefetched x -> inbuf ----
        if constexpr (L == 0) {
            short8_t s;
            s[0] = (short)f2bf(xa.x); s[1] = (short)f2bf(xa.y);
            s[2] = (short)f2bf(xa.z); s[3] = (short)f2bf(xa.w);
            s[4] = (short)f2bf(xb.x); s[5] = (short)f2bf(xb.y);
            s[6] = (short)f2bf(xb.z); s[7] = (short)f2bf(xb.w);
            *(short8_t*)(inb + si * (RSI * 2) + sj * 16) = s;
        }

        // ---- S2: wave 1 polls (wave 0 may still be publishing prev step) ----
        if (w == 1) {
            const int thr = t + thrAdd;
            while (true) {
                int v;
                asm volatile("global_load_dword %0, %1, off sc0 sc1\n\t"
                             "s_waitcnt vmcnt(0)"
                             : "=&v"(v) : "v"((unsigned long long)pollp) : "memory");
                if (__all(v >= thr)) break;
                __builtin_amdgcn_s_sleep(1);
            }
        }
        __syncthreads();   // B1

        // ---- S3: LLC-coherent loads -> LDS (wave w stages rows 4w..4w+3) ----
        {
            i32x4 r0, r1, r2, r3;
            if constexpr (L == 0) {
                const ushort* rb = h0buf + ((size_t)(b0 + w * 4) * 513 + t) * 512 + lane * 8;
                asm volatile("global_load_dwordx4 %0, %4, off sc0 sc1\n\t"
                             "global_load_dwordx4 %1, %5, off sc0 sc1\n\t"
                             "global_load_dwordx4 %2, %6, off sc0 sc1\n\t"
                             "global_load_dwordx4 %3, %7, off sc0 sc1\n\t"
                             "s_waitcnt vmcnt(0)"
                             : "=&v"(r0), "=&v"(r1), "=&v"(r2), "=&v"(r3)
                             : "v"((unsigned long long)rb),
                               "v"((unsigned long long)(rb + RST0)),
                               "v"((unsigned long long)(rb + 2 * RST0)),
                               "v"((unsigned long long)(rb + 3 * RST0))
                             : "memory");
            } else {
                const ushort* ib = h0buf + ((size_t)(b0 + w * 4) * 513 + (t + 1)) * 512 + lane * 8;
                const ushort* rb = h1par + ((size_t)((t & 1) * 256 + b0 + w * 4)) * 512 + lane * 8;
                i32x4 i0, i1, i2, i3;
                asm volatile("global_load_dwordx4 %0, %4, off sc0 sc1\n\t"
                             "global_load_dwordx4 %1, %5, off sc0 sc1\n\t"
                             "global_load_dwordx4 %2, %6, off sc0 sc1\n\t"
                             "global_load_dwordx4 %3, %7, off sc0 sc1"
                             : "=&v"(i0), "=&v"(i1), "=&v"(i2), "=&v"(i3)
                             : "v"((unsigned long long)ib),
                               "v"((unsigned long long)(ib + RST0)),
                               "v"((unsigned long long)(ib + 2 * RST0)),
                               "v"((unsigned long long)(ib + 3 * RST0))
                             : "memory");
                asm volatile("global_load_dwordx4 %0, %4, off sc0 sc1\n\t"
                             "global_load_dwordx4 %1, %5, off sc0 sc1\n\t"
                             "global_load_dwordx4 %2, %6, off sc0 sc1\n\t"
                             "global_load_dwordx4 %3, %7, off sc0 sc1\n\t"
                             "s_waitcnt vmcnt(0)"
                             : "=&v"(r0), "=&v"(r1), "=&v"(r2), "=&v"(r3)
                             : "v"((unsigned long long)rb),
                               "v"((unsigned long long)(rb + 512)),
                               "v"((unsigned long long)(rb + 2 * 512)),
                               "v"((unsigned long long)(rb + 3 * 512))
                             : "memory");
                *(i32x4*)(inb + (w * 4 + 0) * (RSI * 2) + lane * 16) = i0;
                *(i32x4*)(inb + (w * 4 + 1) * (RSI * 2) + lane * 16) = i1;
                *(i32x4*)(inb + (w * 4 + 2) * (RSI * 2) + lane * 16) = i2;
                *(i32x4*)(inb + (w * 4 + 3) * (RSI * 2) + lane * 16) = i3;
            }
            *(i32x4*)(recb + (w * 4 + 0) * (RSR * 2) + lane * 16) = r0;
            *(i32x4*)(recb + (w * 4 + 1) * (RSR * 2) + lane * 16) = r1;
            *(i32x4*)(recb + (w * 4 + 2) * (RSR * 2) + lane * 16) = r2;
            *(i32x4*)(recb + (w * 4 + 3) * (RSR * 2) + lane * 16) = r3;
        }
        // x prefetch for t+1 (issued after the vmcnt so it isn't waited here)
        if constexpr (L == 0) {
            const int tt = (t + 1) & 511;
            const float* xp = x + ((size_t)(b0 + si) * TSEQ + tt) * NKEYS + sj * 8;
            xa = *(const float4*)xp; xb = *(const float4*)(xp + 4);
        }
        __syncthreads();   // B2: all 32 rows staged

        // ---- S5: MFMA sweep (A from AGPR, B from LDS; 2 subtiles x 2 chains) ----
        f32x4 accA0 = bias4, accB0 = bias4;
        f32x4 accA1 = {0.f, 0.f, 0.f, 0.f}, accB1 = {0.f, 0.f, 0.f, 0.f};
        const char* bpi = inb  + arow * (RSI * 2) + hi4 * 16;
        const char* bpr = recb + arow * (RSR * 2) + hi4 * 16;
        if constexpr (L == 0) { AF_LIST_20(AF_MFMA) }
        else                  { AF_LIST_32(AF_MFMA) }
        asm volatile("s_nop 7\n\ts_nop 7"
                     : "+v"(accA0), "+v"(accA1), "+v"(accB0), "+v"(accB1));
        f32x4 am0 = accA0 + accA1, am1 = accB0 + accB1;

        // ---- S6: elementwise (2 units/lane: batch rows arow and 16+arow) ----
        float ig0 = sigm(am0[0]), fg0 = sigm(am0[1]);
        float gg0 = tanh_f(am0[2]), og0 = sigm(am0[3]);
        c0 = fg0 * c0 + ig0 * gg0;
        float h0f = og0 * tanh_f(c0);
        float ig1 = sigm(am1[0]), fg1 = sigm(am1[1]);
        float gg1 = tanh_f(am1[2]), og1 = sigm(am1[3]);
        c1 = fg1 * c1 + ig1 * gg1;
        float h1f = og1 * tanh_f(c1);
        *(ushort*)(stage + arow * 64 + w * 8 + hi4 * 2)        = f2bf(h0f);
        *(ushort*)(stage + (16 + arow) * 64 + w * 8 + hi4 * 2) = f2bf(h1f);
        if (L == 1 && t == TSEQ - 1) {
            hlast[(size_t)(b0 + arow) * 512 + Uw + hi4]      = h0f;
            hlast[(size_t)(b0 + 16 + arow) * 512 + Uw + hi4] = h1f;
        }
        __syncthreads();   // B3: stage visible

        // ---- S7 (wave 0): coalesced 64-B line publish + flag ----
        if (w == 0) {
            const int row = lane >> 2, q = lane & 3;
            i32x4 s0 = *(const i32x4*)(stage + row * 64 + q * 16);
            i32x4 s1 = *(const i32x4*)(stage + (row + 16) * 64 + q * 16);
            const ushort* d0;
            const ushort* d1;
            if constexpr (L == 0) {
                d0 = h0buf + ((size_t)(b0 + row) * 513 + (t + 1)) * 512 + g * 32 + q * 8;
                d1 = h0buf + ((size_t)(b0 + 16 + row) * 513 + (t + 1)) * 512 + g * 32 + q * 8;
            } else {
                const size_t par = (size_t)((t + 1) & 1) * 256;
                d0 = h1par + (par + b0 + row) * 512 + g * 32 + q * 8;
                d1 = h1par + (par + b0 + 16 + row) * 512 + g * 32 + q * 8;
            }
            asm volatile("global_store_dwordx4 %0, %2, off sc0 sc1\n\t"
                         "global_store_dwordx4 %1, %3, off sc0 sc1\n\t"
                         "s_waitcnt vmcnt(0)"
                         :: "v"((unsigned long long)d0), "v"((unsigned long long)d1),
                            "v"(s0), "v"(s1) : "memory");
            if (tid == 0)
                asm volatile("global_store_dword %0, %1, off sc0 sc1"
                             :: "v"((unsigned long long)myflag), "v"(t + 1) : "memory");
        }
    }
}

__global__ __attribute__((amdgpu_waves_per_eu(2, 2))) __launch_bounds__(512)
void lstm_fused(const float* __restrict__ x,
                const ushort* __restrict__ Wc0, const ushort* __restrict__ Wc1,
                const float* __restrict__ bg0, const float* __restrict__ bg1,
                ushort* __restrict__ h0buf, ushort* __restrict__ h1par,
                float* __restrict__ hlast, int* flags)
{
    __shared__ __align__(16) char smem[86016];   // > 80 KiB: physically 1 block/CU
    const int bid = blockIdx.x;
    if (bid < 128) lstm_body<0>(smem, bid, x, Wc0, bg0, h0buf, h1par, hlast, flags);
    else           lstm_body<1>(smem, bid, x, Wc1, bg1, h0buf, h1par, hlast, flags);
}

__global__ void fc_kernel(const float* __restrict__ hlast, const float* __restrict__ Wfc,
                          const float* __restrict__ bfc, float* __restrict__ out) {
    __shared__ float hs[HIDDEN];
    const int b = blockIdx.x, n = threadIdx.x;   // 128 threads
    for (int k = n; k < HIDDEN; k += 128) hs[k] = hlast[b * HIDDEN + k];
    __syncthreads();
    const float* wr = Wfc + (long)n * HIDDEN;
    float acc = bfc[n];
#pragma unroll 8
    for (int k = 0; k < HIDDEN; ++k) acc += hs[k] * wr[k];
    out[b * 128 + n] = acc;
}

extern "C" void kernel_launch(void* const* d_in, const int* in_sizes, int n_in,
                              void* d_out, int out_size, void* d_ws, size_t ws_size,
                              hipStream_t stream) {
    const float* x    = (const float*)d_in[0];
    const float* Wih0 = (const float*)d_in[1];
    const float* Whh0 = (const float*)d_in[2];
    const float* bih0 = (const float*)d_in[3];
    const float* bhh0 = (const float*)d_in[4];
    const float* Wih1 = (const float*)d_in[5];
    const float* Whh1 = (const float*)d_in[6];
    const float* bih1 = (const float*)d_in[7];
    const float* bhh1 = (const float*)d_in[8];
    const float* Wfc  = (const float*)d_in[9];
    const float* bfc  = (const float*)d_in[10];

    char* ws = (char*)d_ws;
    size_t off = 0;
    auto alloc = [&](size_t bytes) {
        void* p = ws + off;
        off = (off + bytes + 255) & ~(size_t)255;
        return p;
    };
    ushort* Wc0   = (ushort*)alloc(2048UL * 640 * 2);         // 2.62 MB
    ushort* Wc1   = (ushort*)alloc(2048UL * 1024 * 2);        // 4.19 MB
    float*  bg0   = (float*)alloc(2048 * 4);
    float*  bg1   = (float*)alloc(2048 * 4);
    float*  hlast = (float*)alloc(256UL * 512 * 4);           // 0.52 MB
    ushort* h1par = (ushort*)alloc(2UL * 256 * 512 * 2);      // 0.52 MB
    int*    flags = (int*)alloc(65536);                       // 2 layers x 8 tiles x 16 slots x 128 B
    ushort* h0buf = (ushort*)alloc(256UL * 513 * 512 * 2);    // 134.5 MB
    if (ws_size < off) return;

    hipMemsetAsync(flags, 0, 65536, stream);
    init_zeros<<<256, 256, 0, stream>>>(h0buf, h1par);
    cast_w<<<(2048 * 640  + 255) / 256, 256, 0, stream>>>(Wih0, Whh0, Wc0, 128, 640);
    cast_w<<<(2048 * 1024 + 255) / 256, 256, 0, stream>>>(Wih1, Whh1, Wc1, 512, 1024);
    prep_bias<<<8, 256, 0, stream>>>(bih0, bhh0, bih1, bhh1, bg0, bg1);

    {
        void* args[] = { (void*)&x, (void*)&Wc0, (void*)&Wc1, (void*)&bg0, (void*)&bg1,
                         (void*)&h0buf, (void*)&h1par, (void*)&hlast, (void*)&flags };
        hipLaunchCooperativeKernel((const void*)lstm_fused, dim3(256), dim3(512),
                                   args, 0, stream);
    }

    fc_kernel<<<256, 128, 0, stream>>>(hlast, Wfc, bfc, (float*)d_out);
}

// Round 13
// 2183.236 us; speedup vs baseline: 7.8148x; 1.0851x over previous
//
#include <hip/hip_runtime.h>

#define HIDDEN 512
#define TSEQ 512
#define NKEYS 128

typedef short short8_t __attribute__((ext_vector_type(8)));
typedef short short4_t __attribute__((ext_vector_type(4)));
typedef float f32x4 __attribute__((ext_vector_type(4)));
typedef int i32x4 __attribute__((ext_vector_type(4)));

__device__ __forceinline__ ushort f2bf(float f) {
    union { float f; unsigned u; } v; v.f = f;
    unsigned r = (v.u + 0x7FFFu + ((v.u >> 16) & 1u)) >> 16;
    return (ushort)r;
}
__device__ __forceinline__ float sigm(float x) { return 1.0f / (1.0f + __expf(-x)); }
__device__ __forceinline__ float tanh_f(float x) { return 2.0f / (1.0f + __expf(-2.0f * x)) - 1.0f; }

// Plain row-major bf16 cast of [W_ih | W_hh]: Wc[row*K + k].
__global__ void cast_w(const float* __restrict__ Wih, const float* __restrict__ Whh,
                       ushort* __restrict__ Wc, int KIN, int K) {
    long idx = (long)blockIdx.x * blockDim.x + threadIdx.x;
    if (idx >= (long)2048 * K) return;
    int row = (int)(idx / K), k = (int)(idx % K);
    float v = (k < KIN) ? Wih[(long)row * KIN + k] : Whh[(long)row * HIDDEN + (k - KIN)];
    Wc[idx] = f2bf(v);
}

__global__ void prep_bias(const float* __restrict__ a, const float* __restrict__ b,
                          const float* __restrict__ c, const float* __restrict__ d,
                          float* __restrict__ b0, float* __restrict__ b1) {
    int i = blockIdx.x * blockDim.x + threadIdx.x;
    if (i < 2048) { b0[i] = a[i] + b[i]; b1[i] = c[i] + d[i]; }
}

// Zero h0buf slot 0 (h(-1) for L0) and h1par parity 0 (h(-1) for L1).
__global__ void init_zeros(ushort* __restrict__ h0buf, ushort* __restrict__ h1par) {
    int idx = blockIdx.x * blockDim.x + threadIdx.x;   // 65536 threads, ushort4 each
    ushort4 z = {0, 0, 0, 0};
    if (idx < 32768) {
        int b = idx >> 7, off = (idx & 127) * 4;
        *(ushort4*)(h0buf + (size_t)b * 513 * 512 + off) = z;
    } else {
        int j = idx - 32768;
        *(ushort4*)(h1par + (size_t)j * 4) = z;
    }
}

// ---- named weight registers, pinned into AGPRs ----
#define AF_LIST_20(M) M(0)M(1)M(2)M(3)M(4)M(5)M(6)M(7)M(8)M(9)M(10)M(11)M(12)M(13)M(14)M(15)M(16)M(17)M(18)M(19)
#define AF_LIST_32(M) AF_LIST_20(M) M(20)M(21)M(22)M(23)M(24)M(25)M(26)M(27)M(28)M(29)M(30)M(31)

#define AF_DECL(i) short8_t af##i;
#define AF_LOAD(i) af##i = *(const short8_t*)(wsrc + (i) * 32); \
                   asm volatile("" : "+a"(af##i));

// Two M-subtiles (batch rows arow and 16+arow) share each weight fragment.
#define AF_MFMA(i) { \
    const char* _b  = ((i) < KSI) ? (bpi + (i) * 64) : (bpr + ((i) - KSI) * 64); \
    const int   _r16 = ((i) < KSI) ? (16 * INROW) : (16 * RECROW); \
    short8_t bf0 = *(const short8_t*)_b; \
    short8_t bf1 = *(const short8_t*)(_b + _r16); \
    if ((i) & 1) { \
        asm("v_mfma_f32_16x16x32_bf16 %0, %1, %2, %0" : "+v"(accA1) : "a"(af##i), "v"(bf0)); \
        asm("v_mfma_f32_16x16x32_bf16 %0, %1, %2, %0" : "+v"(accB1) : "a"(af##i), "v"(bf1)); \
    } else { \
        asm("v_mfma_f32_16x16x32_bf16 %0, %1, %2, %0" : "+v"(accA0) : "a"(af##i), "v"(bf0)); \
        asm("v_mfma_f32_16x16x32_bf16 %0, %1, %2, %0" : "+v"(accB0) : "a"(af##i), "v"(bf1)); \
    } }

// Fused 2-layer LSTM, layer-pipelined, XCD-local (r12). Round-13 changes:
//  (a) LDS row stride 1056B (was 1040B): 1040 % 128 = 16 -> ds_read_b128 B-frag
//      reads were 8-way bank conflicts (2.475e8 conflict-cycles = ~0.8us/step).
//      1056 % 128 = 32 -> 16 distinct bank-starts -> 4-way.
//  (b) Own-flag poll skip: own block's 64B rec chunk now lives in LDS (recb is
//      parity-double-buffered; compute lanes ds_write own h to recb[par^1] at
//      publish; stage masks the own chunk) -> poll excludes own slot, removing
//      the own publish->LLC->poll round trip from the critical path.
//  (c) Direct publish: shfl-packed 8B sc0sc1 stores from compute lanes (no
//      stage area, no wave0 republish). Per-wave polls. Barriers 3 -> 2.
template <int L>
__device__ __forceinline__ void lstm_body(
    char* smem, int bid,
    const float* __restrict__ x, const ushort* __restrict__ Wc,
    const float* __restrict__ biasc, ushort* __restrict__ h0buf,
    ushort* __restrict__ h1par, float* __restrict__ hlast, int* flags)
{
    constexpr int KIN   = L ? 512 : 128;
    constexpr int K     = KIN + 512;
    constexpr int KSI   = KIN / 32;          // input-half k-steps (4 / 16)
    constexpr int INROW = L ? 1056 : 288;    // inb row stride (bytes), == 32 mod 128
    constexpr int RECROW = 1056;             // recb row stride (bytes)
    constexpr int RECPAR = 32 * RECROW;      // 33792 B per parity
    constexpr size_t RST0 = 513 * 512;       // h0buf batch-row stride (ushorts)

    char* const recb = smem;                 // 2 parities x 32 rows
    char* const inb  = smem + 2 * RECPAR;

    const int tid = threadIdx.x;
    const int tile = bid & 7;                // tile == XCD (bid%8 mapping)
    const int g    = (bid >> 3) & 15;
    const int b0   = tile * 32;
    const int w = tid >> 6, lane = tid & 63, hi4 = lane >> 4, arow = lane & 15;
    const int Uw = g * 32 + w * 4;
    const int row_l = 512 * (arow & 3) + Uw + (arow >> 2);

    int* const ownbase  = flags + (L ? 4096 : 0) + tile * 512;  // 16 slots x 128 B
    int* const prodbase = flags + tile * 512;                   // L0 slots (for L1)
    int* const myflag   = ownbase + g * 32;

    // ---- weights -> AGPRs (once) ----
    AF_LIST_32(AF_DECL)
    {
        const ushort* wsrc = Wc + (size_t)row_l * K + hi4 * 8;
        if constexpr (L == 0) { AF_LIST_20(AF_LOAD) }
        else                  { AF_LIST_32(AF_LOAD) }
    }
    f32x4 bias4;
#pragma unroll
    for (int r = 0; r < 4; ++r) bias4[r] = biasc[512 * r + Uw + hi4];

    // zero recb (own chunk of parity 0 must be 0 = h(-1))
    for (int i = tid; i < 2 * RECPAR / 4; i += 512) ((int*)recb)[i] = 0;

    float c0 = 0.0f, c1 = 0.0f;

    // x prefetch registers (L0): row si, 8 floats at sj*8
    const int si = tid >> 4, sj = tid & 15;
    float4 xa, xb;
    if constexpr (L == 0) {
        const float* xp = x + ((size_t)(b0 + si) * TSEQ) * NKEYS + sj * 8;
        xa = *(const float4*)xp; xb = *(const float4*)(xp + 4);
    }

    const bool notown = (lane >> 2) != g;    // stage lanes 4g..4g+3 skip own chunk
    // poll: own-layer others >= t (own slot skipped via thrOff=-inf); L1 prod >= t+1
    const int* pollp; int thrOff;
    if constexpr (L == 0) {
        pollp = ownbase + (lane & 15) * 32;
        thrOff = ((lane & 15) == g) ? -0x100000 : 0;
    } else {
        const int prod = (lane >> 4) & 1;
        pollp = (prod ? prodbase : ownbase) + (lane & 15) * 32;
        thrOff = prod ? 1 : (((lane & 15) == g) ? -0x100000 : 0);
    }

    __syncthreads();   // recb zeroed

#pragma unroll 1
    for (int t = 0; t < TSEQ; ++t) {
        const int par = t & 1;
        char* const rb_cur = recb + par * RECPAR;
        char* const rb_nxt = recb + (par ^ 1) * RECPAR;

        // ---- x input -> inb (L0; safe: prev step's compute done before B_f) ----
        if constexpr (L == 0) {
            short8_t s;
            s[0] = (short)f2bf(xa.x); s[1] = (short)f2bf(xa.y);
            s[2] = (short)f2bf(xa.z); s[3] = (short)f2bf(xa.w);
            s[4] = (short)f2bf(xb.x); s[5] = (short)f2bf(xb.y);
            s[6] = (short)f2bf(xb.z); s[7] = (short)f2bf(xb.w);
            *(short8_t*)(inb + si * INROW + sj * 16) = s;
        }

        // ---- per-wave poll (15 tile-mates; L1 also L0 producers) ----
        {
            const int thr = t + thrOff;
            while (true) {
                int v;
                asm volatile("global_load_dword %0, %1, off sc0 sc1\n\t"
                             "s_waitcnt vmcnt(0)"
                             : "=&v"(v) : "v"((unsigned long long)pollp) : "memory");
                if (__all(v >= thr)) break;
                __builtin_amdgcn_s_sleep(1);
            }
        }

        // ---- stage: wave w loads rows 4w..4w+3 (rec: own 64B chunk masked) ----
        {
            i32x4 q0, q1, q2, q3;
            if constexpr (L == 1) {
                const ushort* ib = h0buf + ((size_t)(b0 + w * 4) * 513 + (t + 1)) * 512 + lane * 8;
                asm volatile("global_load_dwordx4 %0, %4, off sc0 sc1\n\t"
                             "global_load_dwordx4 %1, %5, off sc0 sc1\n\t"
                             "global_load_dwordx4 %2, %6, off sc0 sc1\n\t"
                             "global_load_dwordx4 %3, %7, off sc0 sc1"
                             : "=&v"(q0), "=&v"(q1), "=&v"(q2), "=&v"(q3)
                             : "v"((unsigned long long)ib),
                               "v"((unsigned long long)(ib + RST0)),
                               "v"((unsigned long long)(ib + 2 * RST0)),
                               "v"((unsigned long long)(ib + 3 * RST0))
                             : "memory");
            }
            i32x4 r0, r1, r2, r3;
            if (notown) {
                const ushort* rb;
                size_t rstr;
                if constexpr (L == 0) {
                    rb = h0buf + ((size_t)(b0 + w * 4) * 513 + t) * 512 + lane * 8;
                    rstr = RST0;
                } else {
                    rb = h1par + ((size_t)(par * 256) + b0 + w * 4) * 512 + lane * 8;
                    rstr = 512;
                }
                asm volatile("global_load_dwordx4 %0, %4, off sc0 sc1\n\t"
                             "global_load_dwordx4 %1, %5, off sc0 sc1\n\t"
                             "global_load_dwordx4 %2, %6, off sc0 sc1\n\t"
                             "global_load_dwordx4 %3, %7, off sc0 sc1"
                             : "=&v"(r0), "=&v"(r1), "=&v"(r2), "=&v"(r3)
                             : "v"((unsigned long long)rb),
                               "v"((unsigned long long)(rb + rstr)),
                               "v"((unsigned long long)(rb + 2 * rstr)),
                               "v"((unsigned long long)(rb + 3 * rstr))
                             : "memory");
            }
            asm volatile("s_waitcnt vmcnt(0)" ::: "memory");
            if constexpr (L == 1) {
                *(i32x4*)(inb + (w * 4 + 0) * INROW + lane * 16) = q0;
                *(i32x4*)(inb + (w * 4 + 1) * INROW + lane * 16) = q1;
                *(i32x4*)(inb + (w * 4 + 2) * INROW + lane * 16) = q2;
                *(i32x4*)(inb + (w * 4 + 3) * INROW + lane * 16) = q3;
            }
            if (notown) {
                *(i32x4*)(rb_cur + (w * 4 + 0) * RECROW + lane * 16) = r0;
                *(i32x4*)(rb_cur + (w * 4 + 1) * RECROW + lane * 16) = r1;
                *(i32x4*)(rb_cur + (w * 4 + 2) * RECROW + lane * 16) = r2;
                *(i32x4*)(rb_cur + (w * 4 + 3) * RECROW + lane * 16) = r3;
            }
        }
        // x prefetch for t+1 (cached path; consumed next step)
        if constexpr (L == 0) {
            const int tt = (t + 1) & 511;
            const float* xp = x + ((size_t)(b0 + si) * TSEQ + tt) * NKEYS + sj * 8;
            xa = *(const float4*)xp; xb = *(const float4*)(xp + 4);
        }
        __syncthreads();   // B_s: all rows staged (own chunks already in LDS)

        // ---- MFMA sweep (A from AGPR, B from LDS; 2 subtiles x 2 chains) ----
        f32x4 accA0 = bias4, accB0 = bias4;
        f32x4 accA1 = {0.f, 0.f, 0.f, 0.f}, accB1 = {0.f, 0.f, 0.f, 0.f};
        const char* bpi = inb + arow * INROW + hi4 * 16;
        const char* bpr = rb_cur + arow * RECROW + hi4 * 16;
        if constexpr (L == 0) { AF_LIST_20(AF_MFMA) }
        else                  { AF_LIST_32(AF_MFMA) }
        asm volatile("s_nop 7\n\ts_nop 7"
                     : "+v"(accA0), "+v"(accA1), "+v"(accB0), "+v"(accB1));
        f32x4 am0 = accA0 + accA1, am1 = accB0 + accB1;

        // ---- elementwise (2 units/lane: batch rows arow and 16+arow) ----
        float ig0 = sigm(am0[0]), fg0 = sigm(am0[1]);
        float gg0 = tanh_f(am0[2]), og0 = sigm(am0[3]);
        c0 = fg0 * c0 + ig0 * gg0;
        float h0f = og0 * tanh_f(c0);
        float ig1 = sigm(am1[0]), fg1 = sigm(am1[1]);
        float gg1 = tanh_f(am1[2]), og1 = sigm(am1[3]);
        c1 = fg1 * c1 + ig1 * gg1;
        float h1f = og1 * tanh_f(c1);
        int hv0 = f2bf(h0f), hv1 = f2bf(h1f);

        // own-slice h -> recb[par^1] (next step's rec; race-free: others read rb_cur)
        *(ushort*)(rb_nxt + arow * RECROW + (Uw + hi4) * 2)        = (ushort)hv0;
        *(ushort*)(rb_nxt + (16 + arow) * RECROW + (Uw + hi4) * 2) = (ushort)hv1;

        // ---- shfl-pack publish (8B sc0sc1 from hi4==0 lanes) ----
        int a0 = __shfl(hv0, arow, 64),      a1 = __shfl(hv0, 16 + arow, 64);
        int a2 = __shfl(hv0, 32 + arow, 64), a3 = __shfl(hv0, 48 + arow, 64);
        int e0 = __shfl(hv1, arow, 64),      e1 = __shfl(hv1, 16 + arow, 64);
        int e2 = __shfl(hv1, 32 + arow, 64), e3 = __shfl(hv1, 48 + arow, 64);
        if (hi4 == 0) {
            unsigned lo0 = (a0 & 0xFFFF) | (a1 << 16);
            unsigned hi0 = (a2 & 0xFFFF) | (a3 << 16);
            unsigned long long pk0 = lo0 | ((unsigned long long)hi0 << 32);
            unsigned lo1 = (e0 & 0xFFFF) | (e1 << 16);
            unsigned hi1 = (e2 & 0xFFFF) | (e3 << 16);
            unsigned long long pk1 = lo1 | ((unsigned long long)hi1 << 32);
            const ushort* d0;
            const ushort* d1;
            if constexpr (L == 0) {
                d0 = h0buf + ((size_t)(b0 + arow) * 513 + (t + 1)) * 512 + Uw;
                d1 = h0buf + ((size_t)(b0 + 16 + arow) * 513 + (t + 1)) * 512 + Uw;
            } else {
                const size_t pr = (size_t)((t + 1) & 1) * 256;
                d0 = h1par + (pr + b0 + arow) * 512 + Uw;
                d1 = h1par + (pr + b0 + 16 + arow) * 512 + Uw;
            }
            asm volatile("global_store_dwordx2 %0, %2, off sc0 sc1\n\t"
                         "global_store_dwordx2 %1, %3, off sc0 sc1"
                         :: "v"((unsigned long long)d0), "v"((unsigned long long)d1),
                            "v"(pk0), "v"(pk1) : "memory");
        }
        if (L == 1 && t == TSEQ - 1) {
            hlast[(size_t)(b0 + arow) * 512 + Uw + hi4]      = h0f;
            hlast[(size_t)(b0 + 16 + arow) * 512 + Uw + hi4] = h1f;
        }

        asm volatile("s_waitcnt vmcnt(0)" ::: "memory");
        __syncthreads();   // B_f: all publishes durable, all LDS writes done
        if (tid == 0)
            asm volatile("global_store_dword %0, %1, off sc0 sc1"
                         :: "v"((unsigned long long)myflag), "v"(t + 1) : "memory");
    }
}

__global__ __attribute__((amdgpu_waves_per_eu(2, 2))) __launch_bounds__(512)
void lstm_fused(const float* __restrict__ x,
                const ushort* __restrict__ Wc0, const ushort* __restrict__ Wc1,
                const float* __restrict__ bg0, const float* __restrict__ bg1,
                ushort* __restrict__ h0buf, ushort* __restrict__ h1par,
                float* __restrict__ hlast, int* flags)
{
    __shared__ __align__(16) char smem[101376];   // 2x33792 recb + 33792 inb; >80KiB -> 1 block/CU
    const int bid = blockIdx.x;
    if (bid < 128) lstm_body<0>(smem, bid, x, Wc0, bg0, h0buf, h1par, hlast, flags);
    else           lstm_body<1>(smem, bid, x, Wc1, bg1, h0buf, h1par, hlast, flags);
}

__global__ void fc_kernel(const float* __restrict__ hlast, const float* __restrict__ Wfc,
                          const float* __restrict__ bfc, float* __restrict__ out) {
    __shared__ float hs[HIDDEN];
    const int b = blockIdx.x, n = threadIdx.x;   // 128 threads
    for (int k = n; k < HIDDEN; k += 128) hs[k] = hlast[b * HIDDEN + k];
    __syncthreads();
    const float* wr = Wfc + (long)n * HIDDEN;
    float acc = bfc[n];
#pragma unroll 8
    for (int k = 0; k < HIDDEN; ++k) acc += hs[k] * wr[k];
    out[b * 128 + n] = acc;
}

extern "C" void kernel_launch(void* const* d_in, const int* in_sizes, int n_in,
                              void* d_out, int out_size, void* d_ws, size_t ws_size,
                              hipStream_t stream) {
    const float* x    = (const float*)d_in[0];
    const float* Wih0 = (const float*)d_in[1];
    const float* Whh0 = (const float*)d_in[2];
    const float* bih0 = (const float*)d_in[3];
    const float* bhh0 = (const float*)d_in[4];
    const float* Wih1 = (const float*)d_in[5];
    const float* Whh1 = (const float*)d_in[6];
    const float* bih1 = (const float*)d_in[7];
    const float* bhh1 = (const float*)d_in[8];
    const float* Wfc  = (const float*)d_in[9];
    const float* bfc  = (const float*)d_in[10];

    char* ws = (char*)d_ws;
    size_t off = 0;
    auto alloc = [&](size_t bytes) {
        void* p = ws + off;
        off = (off + bytes + 255) & ~(size_t)255;
        return p;
    };
    ushort* Wc0   = (ushort*)alloc(2048UL * 640 * 2);         // 2.62 MB
    ushort* Wc1   = (ushort*)alloc(2048UL * 1024 * 2);        // 4.19 MB
    float*  bg0   = (float*)alloc(2048 * 4);
    float*  bg1   = (float*)alloc(2048 * 4);
    float*  hlast = (float*)alloc(256UL * 512 * 4);           // 0.52 MB
    ushort* h1par = (ushort*)alloc(2UL * 256 * 512 * 2);      // 0.52 MB
    int*    flags = (int*)alloc(65536);                       // 2 layers x 8 tiles x 16 slots x 128 B
    ushort* h0buf = (ushort*)alloc(256UL * 513 * 512 * 2);    // 134.5 MB
    if (ws_size < off) return;

    hipMemsetAsync(flags, 0, 65536, stream);
    init_zeros<<<256, 256, 0, stream>>>(h0buf, h1par);
    cast_w<<<(2048 * 640  + 255) / 256, 256, 0, stream>>>(Wih0, Whh0, Wc0, 128, 640);
    cast_w<<<(2048 * 1024 + 255) / 256, 256, 0, stream>>>(Wih1, Whh1, Wc1, 512, 1024);
    prep_bias<<<8, 256, 0, stream>>>(bih0, bhh0, bih1, bhh1, bg0, bg1);

    {
        void* args[] = { (void*)&x, (void*)&Wc0, (void*)&Wc1, (void*)&bg0, (void*)&bg1,
                         (void*)&h0buf, (void*)&h1par, (void*)&hlast, (void*)&flags };
        hipLaunchCooperativeKernel((const void*)lstm_fused, dim3(256), dim3(512),
                                   args, 0, stream);
    }

    fc_kernel<<<256, 128, 0, stream>>>(hlast, Wfc, bfc, (float*)d_out);
}